// Round 1
// baseline (1167.013 us; speedup 1.0000x reference)
//
#include <hip/hip_runtime.h>
#include <cstdint>

#define BB 8
#define LL 4096
#define DD 1024
#define D4 256
#define HH 16
#define KSEL 409
#define NT3 3072

// S pitch 452 (>=448 cols, %32==4 for bank spread), Q pitch 68, KV pitch 64 (swizzled)
#define SP 452
#define ATTN_SMEM ((64 * SP + 64 * 68 + 64 * 64 + 64) * 4)

// ---------------- scorer: z = relu(x@w1+b1)@w2, plus write-through y = x ----
__global__ __launch_bounds__(256, 2) void k_score(
    const float* __restrict__ x, const float* __restrict__ w1,
    const float* __restrict__ b1, const float* __restrict__ w2,
    float* __restrict__ z, float* __restrict__ y) {
  __shared__ float As[64][36];
  __shared__ float Bs[32][256];
  __shared__ float b1s[256], w2s[256];
  const int tid = threadIdx.x;
  b1s[tid] = b1[tid];
  w2s[tid] = w2[tid];
  const long t0 = (long)blockIdx.x * 64;
  const int ty = tid >> 5, tx = tid & 31;
  float acc[8][8];
#pragma unroll
  for (int i = 0; i < 8; i++)
#pragma unroll
    for (int j = 0; j < 8; j++) acc[i][j] = 0.f;
  const int lrow = tid >> 2, lk = (tid & 3) * 8;
  const float* xrow = x + (t0 + lrow) * DD;
  float* yrow = y + (t0 + lrow) * DD;
  const int brow = tid >> 3, bc = (tid & 7) * 32;

  for (int k0 = 0; k0 < DD; k0 += 32) {
    float4 xa = *(const float4*)(xrow + k0 + lk);
    float4 xb = *(const float4*)(xrow + k0 + lk + 4);
    *(float4*)(&As[lrow][lk]) = xa;
    *(float4*)(&As[lrow][lk + 4]) = xb;
    *(float4*)(yrow + k0 + lk) = xa;       // write-through residual copy
    *(float4*)(yrow + k0 + lk + 4) = xb;
    const float* wrow = w1 + (long)(k0 + brow) * D4 + bc;
#pragma unroll
    for (int q = 0; q < 8; q++)
      *(float4*)(&Bs[brow][bc + q * 4]) = *(const float4*)(wrow + q * 4);
    __syncthreads();
#pragma unroll
    for (int kk = 0; kk < 32; kk++) {
      float a[8], bb2[8];
#pragma unroll
      for (int i = 0; i < 8; i++) a[i] = As[ty * 8 + i][kk];
#pragma unroll
      for (int j = 0; j < 8; j++) bb2[j] = Bs[kk][tx + 32 * j];
#pragma unroll
      for (int i = 0; i < 8; i++)
#pragma unroll
        for (int j = 0; j < 8; j++) acc[i][j] = fmaf(a[i], bb2[j], acc[i][j]);
    }
    __syncthreads();
  }
#pragma unroll
  for (int i = 0; i < 8; i++) {
    float p = 0.f;
#pragma unroll
    for (int j = 0; j < 8; j++) {
      const int c = tx + 32 * j;
      float h = acc[i][j] + b1s[c];
      h = h > 0.f ? h : 0.f;
      p = fmaf(h, w2s[c], p);
    }
    p += __shfl_xor(p, 1, 32);
    p += __shfl_xor(p, 2, 32);
    p += __shfl_xor(p, 4, 32);
    p += __shfl_xor(p, 8, 32);
    p += __shfl_xor(p, 16, 32);
    if (tx == 0) z[t0 + ty * 8 + i] = p;
  }
}

// ---------------- per-batch top-k via bitonic sort of 64-bit keys ----------
__global__ __launch_bounds__(1024) void k_topk(const float* __restrict__ z,
                                               int* __restrict__ sel) {
  __shared__ unsigned long long keys[LL];
  __shared__ unsigned int si[512];
  const int b = blockIdx.x;
  const int tid = threadIdx.x;
#pragma unroll
  for (int s = 0; s < 4; s++) {
    const int i = tid + s * 1024;
    unsigned int u = __float_as_uint(z[b * LL + i]);
    u = (u & 0x80000000u) ? ~u : (u | 0x80000000u);  // order-preserving map
    keys[i] = ((unsigned long long)u << 32) | (unsigned int)(LL - 1 - i);
  }
  __syncthreads();
  for (unsigned int k = 2; k <= LL; k <<= 1) {
    for (unsigned int j = k >> 1; j > 0; j >>= 1) {
#pragma unroll
      for (int s = 0; s < 4; s++) {
        const unsigned int i = tid + s * 1024;
        const unsigned int ixj = i ^ j;
        if (ixj > i) {
          const bool up = ((i & k) == 0);
          const unsigned long long a = keys[i], c = keys[ixj];
          if ((a > c) == up) { keys[i] = c; keys[ixj] = a; }
        }
      }
      __syncthreads();
    }
  }
  // ascending sort -> top KSEL keys are at the tail; recover token indices
  if (tid < 512)
    si[tid] = (tid < KSEL) ? (unsigned int)(LL - 1) -
                                 (unsigned int)(keys[LL - KSEL + tid] & 0xFFFFFFFFu)
                           : 0xFFFFFFFFu;
  __syncthreads();
  // sort selected indices ascending for coalesced gather/scatter
  for (unsigned int k = 2; k <= 512; k <<= 1) {
    for (unsigned int j = k >> 1; j > 0; j >>= 1) {
      if (tid < 512) {
        const unsigned int i = tid;
        const unsigned int ixj = i ^ j;
        if (ixj > i) {
          const bool up = ((i & k) == 0);
          const unsigned int a = si[i], c = si[ixj];
          if ((a > c) == up) { si[i] = c; si[ixj] = a; }
        }
      }
      __syncthreads();
    }
  }
  if (tid < KSEL) sel[b * KSEL + tid] = (int)si[tid];
}

// ---------------- gathered QKV projection: qkv = x[sel] @ wqkv -------------
__global__ __launch_bounds__(256, 2) void k_qkv(
    const float* __restrict__ x, const float* __restrict__ wqkv,
    const int* __restrict__ sel, float* __restrict__ qkv) {
  __shared__ float As[64][36];
  __shared__ float Bs[32][256];
  const int tid = threadIdx.x;
  const int nt = blockIdx.x, mt = blockIdx.y, b = blockIdx.z;
  const int ty = tid >> 5, tx = tid & 31;
  float acc[8][8];
#pragma unroll
  for (int i = 0; i < 8; i++)
#pragma unroll
    for (int j = 0; j < 8; j++) acc[i][j] = 0.f;
  const int lrow = tid >> 2, lk = (tid & 3) * 8;
  const int m = mt * 64 + lrow;
  const int tok = (m < KSEL) ? sel[b * KSEL + m] : 0;
  const float* xrow = x + ((long)b * LL + tok) * DD;
  const int brow = tid >> 3, bc = (tid & 7) * 32;
  const float* wbase = wqkv + (long)brow * NT3 + nt * 256 + bc;

  for (int k0 = 0; k0 < DD; k0 += 32) {
    *(float4*)(&As[lrow][lk]) = *(const float4*)(xrow + k0 + lk);
    *(float4*)(&As[lrow][lk + 4]) = *(const float4*)(xrow + k0 + lk + 4);
    const float* wrow = wbase + (long)k0 * NT3;
#pragma unroll
    for (int q = 0; q < 8; q++)
      *(float4*)(&Bs[brow][bc + q * 4]) = *(const float4*)(wrow + q * 4);
    __syncthreads();
#pragma unroll
    for (int kk = 0; kk < 32; kk++) {
      float a[8], bb2[8];
#pragma unroll
      for (int i = 0; i < 8; i++) a[i] = As[ty * 8 + i][kk];
#pragma unroll
      for (int j = 0; j < 8; j++) bb2[j] = Bs[kk][tx + 32 * j];
#pragma unroll
      for (int i = 0; i < 8; i++)
#pragma unroll
        for (int j = 0; j < 8; j++) acc[i][j] = fmaf(a[i], bb2[j], acc[i][j]);
    }
    __syncthreads();
  }
#pragma unroll
  for (int i = 0; i < 8; i++) {
    const int mm = mt * 64 + ty * 8 + i;
    if (mm < KSEL) {
      float* orow = qkv + ((long)b * KSEL + mm) * NT3 + nt * 256;
#pragma unroll
      for (int j = 0; j < 8; j++) orow[tx + 32 * j] = acc[i][j];
    }
  }
}

// ---------------- attention over selected tokens ---------------------------
__global__ __launch_bounds__(256) void k_attn(const float* __restrict__ qkv,
                                              float* __restrict__ ao) {
  extern __shared__ float sm[];
  float* S = sm;                  // [64][SP]
  float* Q = sm + 64 * SP;        // [64][68]
  float* KV = Q + 64 * 68;        // [64][64], XOR-swizzled 16B slots
  float* rsum = KV + 64 * 64;     // [64]
  const int tid = threadIdx.x;
  const int qt = blockIdx.x, h = blockIdx.y, b = blockIdx.z;
  const float* base = qkv + (long)b * KSEL * NT3;
  const int ldr = tid >> 2, ldp = (tid & 3) * 16;
  {
    const int m = qt * 64 + ldr;
#pragma unroll
    for (int q = 0; q < 4; q++) {
      float4 v = (m < KSEL)
          ? *(const float4*)(base + (long)m * NT3 + h * 64 + ldp + q * 4)
          : make_float4(0.f, 0.f, 0.f, 0.f);
      *(float4*)(&Q[ldr * 68 + ldp + q * 4]) = v;
    }
  }
  const int qg = tid >> 4, kg = tid & 15;
  // ---- S = Q K^T ----
  for (int kt = 0; kt < 7; kt++) {
    {
      const int m = kt * 64 + ldr;
#pragma unroll
      for (int q = 0; q < 4; q++) {
        float4 v = (m < KSEL)
            ? *(const float4*)(base + (long)m * NT3 + DD + h * 64 + ldp + q * 4)
            : make_float4(0.f, 0.f, 0.f, 0.f);
        const int slot = ((ldp >> 2) + q) ^ (ldr & 7);
        *(float4*)(&KV[ldr * 64 + slot * 4]) = v;
      }
    }
    __syncthreads();
    float acc[4][4];
#pragma unroll
    for (int i = 0; i < 4; i++)
#pragma unroll
      for (int j = 0; j < 4; j++) acc[i][j] = 0.f;
#pragma unroll
    for (int d0 = 0; d0 < 64; d0 += 4) {
      float4 qv[4], kv[4];
#pragma unroll
      for (int i = 0; i < 4; i++) qv[i] = *(const float4*)(&Q[(qg * 4 + i) * 68 + d0]);
#pragma unroll
      for (int j = 0; j < 4; j++) {
        const int r = kg * 4 + j;
        const int slot = (d0 >> 2) ^ (r & 7);
        kv[j] = *(const float4*)(&KV[r * 64 + slot * 4]);
      }
#pragma unroll
      for (int i = 0; i < 4; i++)
#pragma unroll
        for (int j = 0; j < 4; j++)
          acc[i][j] += qv[i].x * kv[j].x + qv[i].y * kv[j].y +
                       qv[i].z * kv[j].z + qv[i].w * kv[j].w;
    }
#pragma unroll
    for (int i = 0; i < 4; i++)
      *(float4*)(&S[(qg * 4 + i) * SP + kt * 64 + kg * 4]) =
          make_float4(acc[i][0], acc[i][1], acc[i][2], acc[i][3]);
    __syncthreads();
  }
  // ---- softmax rows (scale 1/8); zero the padded tail ----
  {
    const int r = tid >> 2, part = tid & 3;
    float mx = -1e30f;
    for (int c = part; c < KSEL; c += 4) mx = fmaxf(mx, S[r * SP + c]);
    mx = fmaxf(mx, __shfl_xor(mx, 1, 4));
    mx = fmaxf(mx, __shfl_xor(mx, 2, 4));
    float sum = 0.f;
    for (int c = part; c < 448; c += 4) {
      const float e = (c < KSEL) ? __expf((S[r * SP + c] - mx) * 0.125f) : 0.f;
      S[r * SP + c] = e;
      sum += e;
    }
    sum += __shfl_xor(sum, 1, 4);
    sum += __shfl_xor(sum, 2, 4);
    if (part == 0) rsum[r] = sum;
  }
  __syncthreads();
  // ---- O = P V ----
  float o[4][4];
#pragma unroll
  for (int i = 0; i < 4; i++)
#pragma unroll
    for (int j = 0; j < 4; j++) o[i][j] = 0.f;
  for (int kt = 0; kt < 7; kt++) {
    {
      const int m = kt * 64 + ldr;
#pragma unroll
      for (int q = 0; q < 4; q++) {
        float4 v = (m < KSEL)
            ? *(const float4*)(base + (long)m * NT3 + 2 * DD + h * 64 + ldp + q * 4)
            : make_float4(0.f, 0.f, 0.f, 0.f);
        const int slot = ((ldp >> 2) + q) ^ (ldr & 7);
        *(float4*)(&KV[ldr * 64 + slot * 4]) = v;
      }
    }
    __syncthreads();
#pragma unroll 4
    for (int kk = 0; kk < 64; kk++) {
      float p[4];
#pragma unroll
      for (int i = 0; i < 4; i++) p[i] = S[(qg * 4 + i) * SP + kt * 64 + kk];
      const int slot = kg ^ (kk & 7);
      const float4 vv = *(const float4*)(&KV[kk * 64 + slot * 4]);
#pragma unroll
      for (int i = 0; i < 4; i++) {
        o[i][0] = fmaf(p[i], vv.x, o[i][0]);
        o[i][1] = fmaf(p[i], vv.y, o[i][1]);
        o[i][2] = fmaf(p[i], vv.z, o[i][2]);
        o[i][3] = fmaf(p[i], vv.w, o[i][3]);
      }
    }
    __syncthreads();
  }
#pragma unroll
  for (int i = 0; i < 4; i++) {
    const int m = qt * 64 + qg * 4 + i;
    if (m < KSEL) {
      const float inv = 1.0f / rsum[qg * 4 + i];
      float4 v = make_float4(o[i][0] * inv, o[i][1] * inv, o[i][2] * inv, o[i][3] * inv);
      *(float4*)(ao + ((long)b * KSEL + m) * DD + h * 64 + kg * 4) = v;
    }
  }
}

// ---------------- out projection + scatter + residual ----------------------
__global__ __launch_bounds__(256, 2) void k_oproj(
    const float* __restrict__ ao, const float* __restrict__ wout,
    const int* __restrict__ sel, const float* __restrict__ x,
    const float* __restrict__ resw, float* __restrict__ y) {
  __shared__ float As[64][36];
  __shared__ float Bs[32][132];
  const int tid = threadIdx.x;
  const int nt = blockIdx.x, mt = blockIdx.y, b = blockIdx.z;
  const int ty = tid >> 5, tx = tid & 31;
  float acc[8][4];
#pragma unroll
  for (int i = 0; i < 8; i++)
#pragma unroll
    for (int j = 0; j < 4; j++) acc[i][j] = 0.f;
  const int lrow = tid >> 2, lk = (tid & 3) * 8;
  const int m = mt * 64 + lrow;
  const int ar = (m < KSEL) ? m : 0;
  const float* arow = ao + ((long)b * KSEL + ar) * DD;
  const int brow = tid >> 3, bc = (tid & 7) * 16;

  for (int k0 = 0; k0 < DD; k0 += 32) {
    *(float4*)(&As[lrow][lk]) = *(const float4*)(arow + k0 + lk);
    *(float4*)(&As[lrow][lk + 4]) = *(const float4*)(arow + k0 + lk + 4);
    const float* wrow = wout + (long)(k0 + brow) * DD + nt * 128 + bc;
#pragma unroll
    for (int q = 0; q < 4; q++)
      *(float4*)(&Bs[brow][bc + q * 4]) = *(const float4*)(wrow + q * 4);
    __syncthreads();
#pragma unroll
    for (int kk = 0; kk < 32; kk++) {
      float a[8], bb2[4];
#pragma unroll
      for (int i = 0; i < 8; i++) a[i] = As[ty * 8 + i][kk];
#pragma unroll
      for (int j = 0; j < 4; j++) bb2[j] = Bs[kk][tx + 32 * j];
#pragma unroll
      for (int i = 0; i < 8; i++)
#pragma unroll
        for (int j = 0; j < 4; j++) acc[i][j] = fmaf(a[i], bb2[j], acc[i][j]);
    }
    __syncthreads();
  }
  const float rw = resw[0];
#pragma unroll
  for (int i = 0; i < 8; i++) {
    const int mm = mt * 64 + ty * 8 + i;
    if (mm < KSEL) {
      const int tok = sel[b * KSEL + mm];
      const long off = ((long)b * LL + tok) * DD + nt * 128;
#pragma unroll
      for (int j = 0; j < 4; j++)
        y[off + tx + 32 * j] = fmaf(rw, acc[i][j], x[off + tx + 32 * j]);
    }
  }
}

extern "C" void kernel_launch(void* const* d_in, const int* in_sizes, int n_in,
                              void* d_out, int out_size, void* d_ws, size_t ws_size,
                              hipStream_t stream) {
  const float* x = (const float*)d_in[0];
  const float* w1 = (const float*)d_in[1];
  const float* b1 = (const float*)d_in[2];
  const float* w2 = (const float*)d_in[3];
  // d_in[4] = b2: constant shift through monotone sigmoid -> irrelevant to top-k
  const float* wqkv = (const float*)d_in[5];
  const float* wout = (const float*)d_in[6];
  const float* resw = (const float*)d_in[7];
  float* y = (float*)d_out;

  char* ws = (char*)d_ws;
  float* z = (float*)ws;                                   // 32768 f32
  int* sel = (int*)(ws + 131072);                          // 8*409 i32
  float* qkv = (float*)(ws + 147456);                      // 8*409*3072 f32
  float* ao = (float*)(ws + 147456 + 40212480);            // 8*409*1024 f32

  hipFuncSetAttribute(reinterpret_cast<const void*>(k_attn),
                      hipFuncAttributeMaxDynamicSharedMemorySize, ATTN_SMEM);

  k_score<<<512, 256, 0, stream>>>(x, w1, b1, w2, z, y);
  k_topk<<<BB, 1024, 0, stream>>>(z, sel);
  k_qkv<<<dim3(12, 7, BB), 256, 0, stream>>>(x, wqkv, sel, qkv);
  k_attn<<<dim3(7, HH, BB), 256, ATTN_SMEM, stream>>>(qkv, ao);
  k_oproj<<<dim3(8, 7, BB), 256, 0, stream>>>(ao, wout, sel, x, resw, y);
}

// Round 2
// 694.676 us; speedup vs baseline: 1.6799x; 1.6799x over previous
//
#include <hip/hip_runtime.h>
#include <cstdint>

#define BB 8
#define LL 4096
#define DD 1024
#define HH 16
#define KSEL 409
#define NT3 3072
#define MTOT (BB * KSEL)   // 3272 flat selected rows
#define PK 40              // LDS pitch in bf16 for 32-wide k tiles (+8 pad)

typedef unsigned short u16;
typedef __attribute__((ext_vector_type(4))) unsigned int ux4;
typedef __attribute__((ext_vector_type(8))) short short8;
typedef __attribute__((ext_vector_type(4))) float f32x4;

// S pitch 452, Q pitch 68, KV pitch 64 (swizzled) -- attention scratch (unchanged R1)
#define SP 452
#define ATTN_SMEM ((64 * SP + 64 * 68 + 64 * 64 + 64) * 4)

__device__ __forceinline__ u16 bfh(float f) {
  unsigned u = __float_as_uint(f);
  return (u16)((u + 0x7fffu + ((u >> 16) & 1u)) >> 16);
}
__device__ __forceinline__ float bff(u16 h) { return __uint_as_float(((unsigned)h) << 16); }

// 8 consecutive f32 -> 8 hi-bf16 (one ux4) + 8 lo-bf16 (one ux4)
__device__ __forceinline__ void cvt8(const float* v, ux4& H, ux4& L) {
#pragma unroll
  for (int i = 0; i < 4; i++) {
    u16 h0 = bfh(v[2 * i]), h1 = bfh(v[2 * i + 1]);
    u16 l0 = bfh(v[2 * i] - bff(h0));
    u16 l1 = bfh(v[2 * i + 1] - bff(h1));
    H[i] = (unsigned)h0 | ((unsigned)h1 << 16);
    L[i] = (unsigned)l0 | ((unsigned)l1 << 16);
  }
}

// ---------- prep: fp32 weight [K][N] -> split-bf16 K-packed [s][n][32] ----------
__global__ __launch_bounds__(256) void k_prep(const float* __restrict__ w, int N,
                                              u16* __restrict__ h, u16* __restrict__ l) {
  __shared__ float T[32][257];
  const int t = threadIdx.x;
  const int n0 = blockIdx.x * 256, s = blockIdx.y;
#pragma unroll 4
  for (int r = 0; r < 32; r++) T[r][t] = w[((long)(s * 32 + r)) * N + n0 + t];
  __syncthreads();
  const long base = ((long)s * N + n0 + t) * 32;
#pragma unroll
  for (int q = 0; q < 4; q++) {
    float v[8];
#pragma unroll
    for (int i = 0; i < 8; i++) v[i] = T[q * 8 + i][t];
    ux4 H, L;
    cvt8(v, H, L);
    *(ux4*)(h + base + q * 8) = H;
    *(ux4*)(l + base + q * 8) = L;
  }
}

// ---------- scorer: h = x@w1+b1 (4-term split MFMA); z = relu(h)@w2 (fp32) ------
// BM=64, BN=256 (full hidden dim), 4 waves each 32x128
__global__ __launch_bounds__(256) void k_score(
    const float* __restrict__ x, const u16* __restrict__ w1h, const u16* __restrict__ w1l,
    const float* __restrict__ b1, const float* __restrict__ w2,
    float* __restrict__ z, float* __restrict__ y) {
  __shared__ u16 Ah[64 * PK], Al[64 * PK], Bh[256 * PK], Bl[256 * PK];
  __shared__ float zp[64][2];
  const int t = threadIdx.x;
  const long t0 = (long)blockIdx.x * 64;
  const int wid = t >> 6, lane = t & 63;
  const int my = wid >> 1, nx = wid & 1;
  f32x4 acc[2][8];
#pragma unroll
  for (int i = 0; i < 2; i++)
#pragma unroll
    for (int j = 0; j < 8; j++) acc[i][j] = (f32x4){0.f, 0.f, 0.f, 0.f};

  const int ar = t >> 2, ak = (t & 3) * 8;
  const float* xrow = x + (t0 + ar) * DD + ak;
  float* yrow = y + (t0 + ar) * DD + ak;
  const int arow = my * 32 + (lane & 15);
  const int koff = (lane >> 4) * 8;

  for (int s = 0; s < 32; s++) {
    float4 va = *(const float4*)(xrow + s * 32);
    float4 vb = *(const float4*)(xrow + s * 32 + 4);
    *(float4*)(yrow + s * 32) = va;          // write-through residual base y = x
    *(float4*)(yrow + s * 32 + 4) = vb;
    float v[8] = {va.x, va.y, va.z, va.w, vb.x, vb.y, vb.z, vb.w};
    ux4 H, L;
    cvt8(v, H, L);
    *(ux4*)(Ah + ar * PK + ak) = H;
    *(ux4*)(Al + ar * PK + ak) = L;
    const long wb = ((long)s * 256 + t) * 32;
#pragma unroll
    for (int q = 0; q < 4; q++) {
      *(ux4*)(Bh + t * PK + q * 8) = *(const ux4*)(w1h + wb + q * 8);
      *(ux4*)(Bl + t * PK + q * 8) = *(const ux4*)(w1l + wb + q * 8);
    }
    __syncthreads();
    short8 a_h[2], a_l[2];
#pragma unroll
    for (int mi = 0; mi < 2; mi++) {
      a_h[mi] = *(const short8*)(Ah + (arow + mi * 16) * PK + koff);
      a_l[mi] = *(const short8*)(Al + (arow + mi * 16) * PK + koff);
    }
#pragma unroll
    for (int ni = 0; ni < 8; ni++) {
      const int brow = (nx * 128 + ni * 16 + (lane & 15)) * PK + koff;
      short8 b_h = *(const short8*)(Bh + brow);
      short8 b_l = *(const short8*)(Bl + brow);
#pragma unroll
      for (int mi = 0; mi < 2; mi++) {
        acc[mi][ni] = __builtin_amdgcn_mfma_f32_16x16x32_bf16(a_h[mi], b_h, acc[mi][ni], 0, 0, 0);
        acc[mi][ni] = __builtin_amdgcn_mfma_f32_16x16x32_bf16(a_h[mi], b_l, acc[mi][ni], 0, 0, 0);
        acc[mi][ni] = __builtin_amdgcn_mfma_f32_16x16x32_bf16(a_l[mi], b_h, acc[mi][ni], 0, 0, 0);
        acc[mi][ni] = __builtin_amdgcn_mfma_f32_16x16x32_bf16(a_l[mi], b_l, acc[mi][ni], 0, 0, 0);
      }
    }
    __syncthreads();
  }
  // epilogue: relu + second layer (fp32), cross-lane then cross-wave reduce
  float part[2][4];
#pragma unroll
  for (int mi = 0; mi < 2; mi++)
#pragma unroll
    for (int r = 0; r < 4; r++) part[mi][r] = 0.f;
#pragma unroll
  for (int ni = 0; ni < 8; ni++) {
    const int col = nx * 128 + ni * 16 + (lane & 15);
    const float b1v = b1[col], w2v = w2[col];
#pragma unroll
    for (int mi = 0; mi < 2; mi++)
#pragma unroll
      for (int r = 0; r < 4; r++) {
        float hv = acc[mi][ni][r] + b1v;
        hv = hv > 0.f ? hv : 0.f;
        part[mi][r] = fmaf(hv, w2v, part[mi][r]);
      }
  }
#pragma unroll
  for (int mi = 0; mi < 2; mi++)
#pragma unroll
    for (int r = 0; r < 4; r++) {
      float p = part[mi][r];
      p += __shfl_xor(p, 1, 16);
      p += __shfl_xor(p, 2, 16);
      p += __shfl_xor(p, 4, 16);
      p += __shfl_xor(p, 8, 16);
      part[mi][r] = p;
    }
  if ((lane & 15) == 0) {
#pragma unroll
    for (int mi = 0; mi < 2; mi++)
#pragma unroll
      for (int r = 0; r < 4; r++)
        zp[my * 32 + mi * 16 + (lane >> 4) * 4 + r][nx] = part[mi][r];
  }
  __syncthreads();
  if (t < 64) z[t0 + t] = zp[t][0] + zp[t][1];
}

// ---------- per-batch top-k via bitonic sort (unchanged R1) ----------
__global__ __launch_bounds__(1024) void k_topk(const float* __restrict__ z,
                                               int* __restrict__ sel) {
  __shared__ unsigned long long keys[LL];
  __shared__ unsigned int si[512];
  const int b = blockIdx.x;
  const int tid = threadIdx.x;
#pragma unroll
  for (int s = 0; s < 4; s++) {
    const int i = tid + s * 1024;
    unsigned int u = __float_as_uint(z[b * LL + i]);
    u = (u & 0x80000000u) ? ~u : (u | 0x80000000u);
    keys[i] = ((unsigned long long)u << 32) | (unsigned int)(LL - 1 - i);
  }
  __syncthreads();
  for (unsigned int k = 2; k <= LL; k <<= 1) {
    for (unsigned int j = k >> 1; j > 0; j >>= 1) {
#pragma unroll
      for (int s = 0; s < 4; s++) {
        const unsigned int i = tid + s * 1024;
        const unsigned int ixj = i ^ j;
        if (ixj > i) {
          const bool up = ((i & k) == 0);
          const unsigned long long a = keys[i], c = keys[ixj];
          if ((a > c) == up) { keys[i] = c; keys[ixj] = a; }
        }
      }
      __syncthreads();
    }
  }
  if (tid < 512)
    si[tid] = (tid < KSEL) ? (unsigned int)(LL - 1) -
                                 (unsigned int)(keys[LL - KSEL + tid] & 0xFFFFFFFFu)
                           : 0xFFFFFFFFu;
  __syncthreads();
  for (unsigned int k = 2; k <= 512; k <<= 1) {
    for (unsigned int j = k >> 1; j > 0; j >>= 1) {
      if (tid < 512) {
        const unsigned int i = tid;
        const unsigned int ixj = i ^ j;
        if (ixj > i) {
          const bool up = ((i & k) == 0);
          const unsigned int a = si[i], c = si[ixj];
          if ((a > c) == up) { si[i] = c; si[ixj] = a; }
        }
      }
      __syncthreads();
    }
  }
  if (tid < KSEL) sel[b * KSEL + tid] = (int)si[tid];
}

// ---------- qkv = gather(x)[3272] @ wqkv : 3-term split MFMA, 128x128 tile ------
__global__ __launch_bounds__(256) void k_qkv(
    const float* __restrict__ x, const u16* __restrict__ wh, const u16* __restrict__ wl,
    const int* __restrict__ sel, float* __restrict__ qkv) {
  __shared__ u16 Ah[128 * PK], Al[128 * PK], Bh[128 * PK], Bl[128 * PK];
  const int t = threadIdx.x;
  const int nt = blockIdx.x, r0 = blockIdx.y * 128;
  const int wid = t >> 6, lane = t & 63;
  const int wy = wid >> 1, wx = wid & 1;
  f32x4 acc[4][4];
#pragma unroll
  for (int i = 0; i < 4; i++)
#pragma unroll
    for (int j = 0; j < 4; j++) acc[i][j] = (f32x4){0.f, 0.f, 0.f, 0.f};

  const int ar = t >> 1, akk = (t & 1) * 16;
  int rg = r0 + ar;
  rg = rg < MTOT ? rg : MTOT - 1;
  const int bb = rg / KSEL;
  const int tok = sel[rg];
  const float* xr = x + ((long)bb * LL + tok) * DD + akk;
  const int bn = t >> 1, bko = (t & 1) * 16;
  const int arow = wy * 64 + (lane & 15);
  const int koff = (lane >> 4) * 8;

  for (int s = 0; s < 32; s++) {
    float v[16];
#pragma unroll
    for (int q = 0; q < 4; q++) {
      float4 f = *(const float4*)(xr + s * 32 + q * 4);
      v[q * 4] = f.x; v[q * 4 + 1] = f.y; v[q * 4 + 2] = f.z; v[q * 4 + 3] = f.w;
    }
    ux4 H0, L0, H1, L1;
    cvt8(v, H0, L0);
    cvt8(v + 8, H1, L1);
    *(ux4*)(Ah + ar * PK + akk) = H0;
    *(ux4*)(Ah + ar * PK + akk + 8) = H1;
    *(ux4*)(Al + ar * PK + akk) = L0;
    *(ux4*)(Al + ar * PK + akk + 8) = L1;
    const long wb = ((long)s * NT3 + nt * 128 + bn) * 32 + bko;
    *(ux4*)(Bh + bn * PK + bko) = *(const ux4*)(wh + wb);
    *(ux4*)(Bh + bn * PK + bko + 8) = *(const ux4*)(wh + wb + 8);
    *(ux4*)(Bl + bn * PK + bko) = *(const ux4*)(wl + wb);
    *(ux4*)(Bl + bn * PK + bko + 8) = *(const ux4*)(wl + wb + 8);
    __syncthreads();
    short8 a_h[4], a_l[4];
#pragma unroll
    for (int mi = 0; mi < 4; mi++) {
      a_h[mi] = *(const short8*)(Ah + (arow + mi * 16) * PK + koff);
      a_l[mi] = *(const short8*)(Al + (arow + mi * 16) * PK + koff);
    }
#pragma unroll
    for (int ni = 0; ni < 4; ni++) {
      const int brow = (wx * 64 + ni * 16 + (lane & 15)) * PK + koff;
      short8 b_h = *(const short8*)(Bh + brow);
      short8 b_l = *(const short8*)(Bl + brow);
#pragma unroll
      for (int mi = 0; mi < 4; mi++) {
        acc[mi][ni] = __builtin_amdgcn_mfma_f32_16x16x32_bf16(a_h[mi], b_h, acc[mi][ni], 0, 0, 0);
        acc[mi][ni] = __builtin_amdgcn_mfma_f32_16x16x32_bf16(a_h[mi], b_l, acc[mi][ni], 0, 0, 0);
        acc[mi][ni] = __builtin_amdgcn_mfma_f32_16x16x32_bf16(a_l[mi], b_h, acc[mi][ni], 0, 0, 0);
      }
    }
    __syncthreads();
  }
#pragma unroll
  for (int mi = 0; mi < 4; mi++)
#pragma unroll
    for (int rr = 0; rr < 4; rr++) {
      const int r = r0 + wy * 64 + mi * 16 + (lane >> 4) * 4 + rr;
      if (r < MTOT) {
        float* orow = qkv + (long)r * NT3 + nt * 128 + wx * 64 + (lane & 15);
#pragma unroll
        for (int ni = 0; ni < 4; ni++) orow[ni * 16] = acc[mi][ni][rr];
      }
    }
}

// ---------- attention over selected tokens (fp32, unchanged R1) ----------
__global__ __launch_bounds__(256) void k_attn(const float* __restrict__ qkv,
                                              float* __restrict__ ao) {
  extern __shared__ float sm[];
  float* S = sm;
  float* Q = sm + 64 * SP;
  float* KV = Q + 64 * 68;
  float* rsum = KV + 64 * 64;
  const int tid = threadIdx.x;
  const int qt = blockIdx.x, h = blockIdx.y, b = blockIdx.z;
  const float* base = qkv + (long)b * KSEL * NT3;
  const int ldr = tid >> 2, ldp = (tid & 3) * 16;
  {
    const int m = qt * 64 + ldr;
#pragma unroll
    for (int q = 0; q < 4; q++) {
      float4 v = (m < KSEL)
          ? *(const float4*)(base + (long)m * NT3 + h * 64 + ldp + q * 4)
          : make_float4(0.f, 0.f, 0.f, 0.f);
      *(float4*)(&Q[ldr * 68 + ldp + q * 4]) = v;
    }
  }
  const int qg = tid >> 4, kg = tid & 15;
  for (int kt = 0; kt < 7; kt++) {
    {
      const int m = kt * 64 + ldr;
#pragma unroll
      for (int q = 0; q < 4; q++) {
        float4 v = (m < KSEL)
            ? *(const float4*)(base + (long)m * NT3 + DD + h * 64 + ldp + q * 4)
            : make_float4(0.f, 0.f, 0.f, 0.f);
        const int slot = ((ldp >> 2) + q) ^ (ldr & 7);
        *(float4*)(&KV[ldr * 64 + slot * 4]) = v;
      }
    }
    __syncthreads();
    float acc[4][4];
#pragma unroll
    for (int i = 0; i < 4; i++)
#pragma unroll
      for (int j = 0; j < 4; j++) acc[i][j] = 0.f;
#pragma unroll
    for (int d0 = 0; d0 < 64; d0 += 4) {
      float4 qv[4], kv[4];
#pragma unroll
      for (int i = 0; i < 4; i++) qv[i] = *(const float4*)(&Q[(qg * 4 + i) * 68 + d0]);
#pragma unroll
      for (int j = 0; j < 4; j++) {
        const int r = kg * 4 + j;
        const int slot = (d0 >> 2) ^ (r & 7);
        kv[j] = *(const float4*)(&KV[r * 64 + slot * 4]);
      }
#pragma unroll
      for (int i = 0; i < 4; i++)
#pragma unroll
        for (int j = 0; j < 4; j++)
          acc[i][j] += qv[i].x * kv[j].x + qv[i].y * kv[j].y +
                       qv[i].z * kv[j].z + qv[i].w * kv[j].w;
    }
#pragma unroll
    for (int i = 0; i < 4; i++)
      *(float4*)(&S[(qg * 4 + i) * SP + kt * 64 + kg * 4]) =
          make_float4(acc[i][0], acc[i][1], acc[i][2], acc[i][3]);
    __syncthreads();
  }
  {
    const int r = tid >> 2, part = tid & 3;
    float mx = -1e30f;
    for (int c = part; c < KSEL; c += 4) mx = fmaxf(mx, S[r * SP + c]);
    mx = fmaxf(mx, __shfl_xor(mx, 1, 4));
    mx = fmaxf(mx, __shfl_xor(mx, 2, 4));
    float sum = 0.f;
    for (int c = part; c < 448; c += 4) {
      const float e = (c < KSEL) ? __expf((S[r * SP + c] - mx) * 0.125f) : 0.f;
      S[r * SP + c] = e;
      sum += e;
    }
    sum += __shfl_xor(sum, 1, 4);
    sum += __shfl_xor(sum, 2, 4);
    if (part == 0) rsum[r] = sum;
  }
  __syncthreads();
  float o[4][4];
#pragma unroll
  for (int i = 0; i < 4; i++)
#pragma unroll
    for (int j = 0; j < 4; j++) o[i][j] = 0.f;
  for (int kt = 0; kt < 7; kt++) {
    {
      const int m = kt * 64 + ldr;
#pragma unroll
      for (int q = 0; q < 4; q++) {
        float4 v = (m < KSEL)
            ? *(const float4*)(base + (long)m * NT3 + 2 * DD + h * 64 + ldp + q * 4)
            : make_float4(0.f, 0.f, 0.f, 0.f);
        const int slot = ((ldp >> 2) + q) ^ (ldr & 7);
        *(float4*)(&KV[ldr * 64 + slot * 4]) = v;
      }
    }
    __syncthreads();
#pragma unroll 4
    for (int kk = 0; kk < 64; kk++) {
      float p[4];
#pragma unroll
      for (int i = 0; i < 4; i++) p[i] = S[(qg * 4 + i) * SP + kt * 64 + kk];
      const int slot = kg ^ (kk & 7);
      const float4 vv = *(const float4*)(&KV[kk * 64 + slot * 4]);
#pragma unroll
      for (int i = 0; i < 4; i++) {
        o[i][0] = fmaf(p[i], vv.x, o[i][0]);
        o[i][1] = fmaf(p[i], vv.y, o[i][1]);
        o[i][2] = fmaf(p[i], vv.z, o[i][2]);
        o[i][3] = fmaf(p[i], vv.w, o[i][3]);
      }
    }
    __syncthreads();
  }
#pragma unroll
  for (int i = 0; i < 4; i++) {
    const int m = qt * 64 + qg * 4 + i;
    if (m < KSEL) {
      const float inv = 1.0f / rsum[qg * 4 + i];
      float4 v = make_float4(o[i][0] * inv, o[i][1] * inv, o[i][2] * inv, o[i][3] * inv);
      *(float4*)(ao + ((long)b * KSEL + m) * DD + h * 64 + kg * 4) = v;
    }
  }
}

// ---------- out-proj + scatter + residual : 3-term split MFMA ----------
__global__ __launch_bounds__(256) void k_oproj(
    const float* __restrict__ ao, const u16* __restrict__ wh, const u16* __restrict__ wl,
    const int* __restrict__ sel, const float* __restrict__ x,
    const float* __restrict__ resw, float* __restrict__ y) {
  __shared__ u16 Ah[128 * PK], Al[128 * PK], Bh[128 * PK], Bl[128 * PK];
  const int t = threadIdx.x;
  const int nt = blockIdx.x, r0 = blockIdx.y * 128;
  const int wid = t >> 6, lane = t & 63;
  const int wy = wid >> 1, wx = wid & 1;
  f32x4 acc[4][4];
#pragma unroll
  for (int i = 0; i < 4; i++)
#pragma unroll
    for (int j = 0; j < 4; j++) acc[i][j] = (f32x4){0.f, 0.f, 0.f, 0.f};

  const int ar = t >> 1, akk = (t & 1) * 16;
  int rg = r0 + ar;
  rg = rg < MTOT ? rg : MTOT - 1;
  const float* arp = ao + (long)rg * DD + akk;
  const int bn = t >> 1, bko = (t & 1) * 16;
  const int arow = wy * 64 + (lane & 15);
  const int koff = (lane >> 4) * 8;

  for (int s = 0; s < 32; s++) {
    float v[16];
#pragma unroll
    for (int q = 0; q < 4; q++) {
      float4 f = *(const float4*)(arp + s * 32 + q * 4);
      v[q * 4] = f.x; v[q * 4 + 1] = f.y; v[q * 4 + 2] = f.z; v[q * 4 + 3] = f.w;
    }
    ux4 H0, L0, H1, L1;
    cvt8(v, H0, L0);
    cvt8(v + 8, H1, L1);
    *(ux4*)(Ah + ar * PK + akk) = H0;
    *(ux4*)(Ah + ar * PK + akk + 8) = H1;
    *(ux4*)(Al + ar * PK + akk) = L0;
    *(ux4*)(Al + ar * PK + akk + 8) = L1;
    const long wb = ((long)s * DD + nt * 128 + bn) * 32 + bko;
    *(ux4*)(Bh + bn * PK + bko) = *(const ux4*)(wh + wb);
    *(ux4*)(Bh + bn * PK + bko + 8) = *(const ux4*)(wh + wb + 8);
    *(ux4*)(Bl + bn * PK + bko) = *(const ux4*)(wl + wb);
    *(ux4*)(Bl + bn * PK + bko + 8) = *(const ux4*)(wl + wb + 8);
    __syncthreads();
    short8 a_h[4], a_l[4];
#pragma unroll
    for (int mi = 0; mi < 4; mi++) {
      a_h[mi] = *(const short8*)(Ah + (arow + mi * 16) * PK + koff);
      a_l[mi] = *(const short8*)(Al + (arow + mi * 16) * PK + koff);
    }
#pragma unroll
    for (int ni = 0; ni < 4; ni++) {
      const int brow = (wx * 64 + ni * 16 + (lane & 15)) * PK + koff;
      short8 b_h = *(const short8*)(Bh + brow);
      short8 b_l = *(const short8*)(Bl + brow);
#pragma unroll
      for (int mi = 0; mi < 4; mi++) {
        acc[mi][ni] = __builtin_amdgcn_mfma_f32_16x16x32_bf16(a_h[mi], b_h, acc[mi][ni], 0, 0, 0);
        acc[mi][ni] = __builtin_amdgcn_mfma_f32_16x16x32_bf16(a_h[mi], b_l, acc[mi][ni], 0, 0, 0);
        acc[mi][ni] = __builtin_amdgcn_mfma_f32_16x16x32_bf16(a_l[mi], b_h, acc[mi][ni], 0, 0, 0);
      }
    }
    __syncthreads();
  }
  const float rw = resw[0];
#pragma unroll
  for (int mi = 0; mi < 4; mi++)
#pragma unroll
    for (int rr = 0; rr < 4; rr++) {
      const int r = r0 + wy * 64 + mi * 16 + (lane >> 4) * 4 + rr;
      if (r < MTOT) {
        const int bb = r / KSEL;
        const int tok = sel[r];
        const long off = ((long)bb * LL + tok) * DD + nt * 128 + wx * 64 + (lane & 15);
#pragma unroll
        for (int ni = 0; ni < 4; ni++)
          y[off + ni * 16] = fmaf(rw, acc[mi][ni][rr], x[off + ni * 16]);
      }
    }
}

extern "C" void kernel_launch(void* const* d_in, const int* in_sizes, int n_in,
                              void* d_out, int out_size, void* d_ws, size_t ws_size,
                              hipStream_t stream) {
  const float* x = (const float*)d_in[0];
  const float* w1 = (const float*)d_in[1];
  const float* b1 = (const float*)d_in[2];
  const float* w2 = (const float*)d_in[3];
  // d_in[4] = b2: constant shift through monotone sigmoid -> irrelevant to top-k
  const float* wqkv = (const float*)d_in[5];
  const float* wout = (const float*)d_in[6];
  const float* resw = (const float*)d_in[7];
  float* y = (float*)d_out;

  char* ws = (char*)d_ws;
  float* z = (float*)(ws);                  // 131072 B
  int* sel = (int*)(ws + 131072);           // 16384 B
  u16* w1h = (u16*)(ws + 147456);           // 524288 B
  u16* w1l = (u16*)(ws + 671744);           // 524288 B
  u16* wqh = (u16*)(ws + 1196032);          // 6291456 B
  u16* wql = (u16*)(ws + 7487488);          // 6291456 B
  u16* woh = (u16*)(ws + 13778944);         // 2097152 B
  u16* wol = (u16*)(ws + 15876096);         // 2097152 B
  float* qkv = (float*)(ws + 17973248);     // 40206336 B
  float* ao = (float*)(ws + 58179584);      // 13402112 B  -> 71.6 MB total

  hipFuncSetAttribute(reinterpret_cast<const void*>(k_attn),
                      hipFuncAttributeMaxDynamicSharedMemorySize, ATTN_SMEM);

  k_prep<<<dim3(1, 32), 256, 0, stream>>>(w1, 256, w1h, w1l);
  k_prep<<<dim3(12, 32), 256, 0, stream>>>(wqkv, NT3, wqh, wql);
  k_prep<<<dim3(4, 32), 256, 0, stream>>>(wout, DD, woh, wol);
  k_score<<<512, 256, 0, stream>>>(x, w1h, w1l, b1, w2, z, y);
  k_topk<<<BB, 1024, 0, stream>>>(z, sel);
  k_qkv<<<dim3(24, 26), 256, 0, stream>>>(x, wqh, wql, sel, qkv);
  k_attn<<<dim3(7, HH, BB), 256, ATTN_SMEM, stream>>>(qkv, ao);
  k_oproj<<<dim3(8, 26), 256, 0, stream>>>(ao, woh, wol, sel, x, resw, y);
}

// Round 3
// 406.459 us; speedup vs baseline: 2.8712x; 1.7091x over previous
//
#include <hip/hip_runtime.h>
#include <cstdint>

#define BB 8
#define LL 4096
#define DD 1024
#define HH 16
#define KSEL 409
#define NT3 3072
#define MTOT (BB * KSEL)   // 3272 flat selected rows
#define PK 40              // LDS pitch in bf16 for 32-wide k tiles (+8 pad)
#define VP 448             // vT key-pitch (>=448 so kt=6 reads stay in-row)

typedef unsigned short u16;
typedef __attribute__((ext_vector_type(4))) unsigned int ux4;
typedef __attribute__((ext_vector_type(8))) short short8;
typedef __attribute__((ext_vector_type(4))) float f32x4;

__device__ __forceinline__ u16 bfh(float f) {
  unsigned u = __float_as_uint(f);
  return (u16)((u + 0x7fffu + ((u >> 16) & 1u)) >> 16);
}
__device__ __forceinline__ float bff(u16 h) { return __uint_as_float(((unsigned)h) << 16); }

// 8 consecutive f32 -> 8 hi-bf16 (one ux4) + 8 lo-bf16 (one ux4)
__device__ __forceinline__ void cvt8(const float* v, ux4& H, ux4& L) {
#pragma unroll
  for (int i = 0; i < 4; i++) {
    u16 h0 = bfh(v[2 * i]), h1 = bfh(v[2 * i + 1]);
    u16 l0 = bfh(v[2 * i] - bff(h0));
    u16 l1 = bfh(v[2 * i + 1] - bff(h1));
    H[i] = (unsigned)h0 | ((unsigned)h1 << 16);
    L[i] = (unsigned)l0 | ((unsigned)l1 << 16);
  }
}

// ---------- prep: fp32 weight [K][N] -> split-bf16 K-packed [s][n][32] ----------
__global__ __launch_bounds__(256) void k_prep(const float* __restrict__ w, int N,
                                              u16* __restrict__ h, u16* __restrict__ l) {
  __shared__ float T[32][257];
  const int t = threadIdx.x;
  const int n0 = blockIdx.x * 256, s = blockIdx.y;
#pragma unroll 4
  for (int r = 0; r < 32; r++) T[r][t] = w[((long)(s * 32 + r)) * N + n0 + t];
  __syncthreads();
  const long base = ((long)s * N + n0 + t) * 32;
#pragma unroll
  for (int q = 0; q < 4; q++) {
    float v[8];
#pragma unroll
    for (int i = 0; i < 8; i++) v[i] = T[q * 8 + i][t];
    ux4 H, L;
    cvt8(v, H, L);
    *(ux4*)(h + base + q * 8) = H;
    *(ux4*)(l + base + q * 8) = L;
  }
}

// ---------- scorer: h = x@w1+b1 (4-term split MFMA); z = relu(h)@w2 (fp32) ------
__global__ __launch_bounds__(256) void k_score(
    const float* __restrict__ x, const u16* __restrict__ w1h, const u16* __restrict__ w1l,
    const float* __restrict__ b1, const float* __restrict__ w2,
    float* __restrict__ z, float* __restrict__ y) {
  __shared__ u16 Ah[64 * PK], Al[64 * PK], Bh[256 * PK], Bl[256 * PK];
  __shared__ float zp[64][2];
  const int t = threadIdx.x;
  const long t0 = (long)blockIdx.x * 64;
  const int wid = t >> 6, lane = t & 63;
  const int my = wid >> 1, nx = wid & 1;
  f32x4 acc[2][8];
#pragma unroll
  for (int i = 0; i < 2; i++)
#pragma unroll
    for (int j = 0; j < 8; j++) acc[i][j] = (f32x4){0.f, 0.f, 0.f, 0.f};

  const int ar = t >> 2, ak = (t & 3) * 8;
  const float* xrow = x + (t0 + ar) * DD + ak;
  float* yrow = y + (t0 + ar) * DD + ak;
  const int arow = my * 32 + (lane & 15);
  const int koff = (lane >> 4) * 8;

  for (int s = 0; s < 32; s++) {
    float4 va = *(const float4*)(xrow + s * 32);
    float4 vb = *(const float4*)(xrow + s * 32 + 4);
    *(float4*)(yrow + s * 32) = va;          // write-through residual base y = x
    *(float4*)(yrow + s * 32 + 4) = vb;
    float v[8] = {va.x, va.y, va.z, va.w, vb.x, vb.y, vb.z, vb.w};
    ux4 H, L;
    cvt8(v, H, L);
    *(ux4*)(Ah + ar * PK + ak) = H;
    *(ux4*)(Al + ar * PK + ak) = L;
    const long wb = ((long)s * 256 + t) * 32;
#pragma unroll
    for (int q = 0; q < 4; q++) {
      *(ux4*)(Bh + t * PK + q * 8) = *(const ux4*)(w1h + wb + q * 8);
      *(ux4*)(Bl + t * PK + q * 8) = *(const ux4*)(w1l + wb + q * 8);
    }
    __syncthreads();
    short8 a_h[2], a_l[2];
#pragma unroll
    for (int mi = 0; mi < 2; mi++) {
      a_h[mi] = *(const short8*)(Ah + (arow + mi * 16) * PK + koff);
      a_l[mi] = *(const short8*)(Al + (arow + mi * 16) * PK + koff);
    }
#pragma unroll
    for (int ni = 0; ni < 8; ni++) {
      const int brow = (nx * 128 + ni * 16 + (lane & 15)) * PK + koff;
      short8 b_h = *(const short8*)(Bh + brow);
      short8 b_l = *(const short8*)(Bl + brow);
#pragma unroll
      for (int mi = 0; mi < 2; mi++) {
        acc[mi][ni] = __builtin_amdgcn_mfma_f32_16x16x32_bf16(a_h[mi], b_h, acc[mi][ni], 0, 0, 0);
        acc[mi][ni] = __builtin_amdgcn_mfma_f32_16x16x32_bf16(a_h[mi], b_l, acc[mi][ni], 0, 0, 0);
        acc[mi][ni] = __builtin_amdgcn_mfma_f32_16x16x32_bf16(a_l[mi], b_h, acc[mi][ni], 0, 0, 0);
        acc[mi][ni] = __builtin_amdgcn_mfma_f32_16x16x32_bf16(a_l[mi], b_l, acc[mi][ni], 0, 0, 0);
      }
    }
    __syncthreads();
  }
  float part[2][4];
#pragma unroll
  for (int mi = 0; mi < 2; mi++)
#pragma unroll
    for (int r = 0; r < 4; r++) part[mi][r] = 0.f;
#pragma unroll
  for (int ni = 0; ni < 8; ni++) {
    const int col = nx * 128 + ni * 16 + (lane & 15);
    const float b1v = b1[col], w2v = w2[col];
#pragma unroll
    for (int mi = 0; mi < 2; mi++)
#pragma unroll
      for (int r = 0; r < 4; r++) {
        float hv = acc[mi][ni][r] + b1v;
        hv = hv > 0.f ? hv : 0.f;
        part[mi][r] = fmaf(hv, w2v, part[mi][r]);
      }
  }
#pragma unroll
  for (int mi = 0; mi < 2; mi++)
#pragma unroll
    for (int r = 0; r < 4; r++) {
      float p = part[mi][r];
      p += __shfl_xor(p, 1, 16);
      p += __shfl_xor(p, 2, 16);
      p += __shfl_xor(p, 4, 16);
      p += __shfl_xor(p, 8, 16);
      part[mi][r] = p;
    }
  if ((lane & 15) == 0) {
#pragma unroll
    for (int mi = 0; mi < 2; mi++)
#pragma unroll
      for (int r = 0; r < 4; r++)
        zp[my * 32 + mi * 16 + (lane >> 4) * 4 + r][nx] = part[mi][r];
  }
  __syncthreads();
  if (t < 64) z[t0 + t] = zp[t][0] + zp[t][1];
}

// ---------- per-batch top-k via bitonic sort ----------
__global__ __launch_bounds__(1024) void k_topk(const float* __restrict__ z,
                                               int* __restrict__ sel) {
  __shared__ unsigned long long keys[LL];
  __shared__ unsigned int si[512];
  const int b = blockIdx.x;
  const int tid = threadIdx.x;
#pragma unroll
  for (int s = 0; s < 4; s++) {
    const int i = tid + s * 1024;
    unsigned int u = __float_as_uint(z[b * LL + i]);
    u = (u & 0x80000000u) ? ~u : (u | 0x80000000u);
    keys[i] = ((unsigned long long)u << 32) | (unsigned int)(LL - 1 - i);
  }
  __syncthreads();
  for (unsigned int k = 2; k <= LL; k <<= 1) {
    for (unsigned int j = k >> 1; j > 0; j >>= 1) {
#pragma unroll
      for (int s = 0; s < 4; s++) {
        const unsigned int i = tid + s * 1024;
        const unsigned int ixj = i ^ j;
        if (ixj > i) {
          const bool up = ((i & k) == 0);
          const unsigned long long a = keys[i], c = keys[ixj];
          if ((a > c) == up) { keys[i] = c; keys[ixj] = a; }
        }
      }
      __syncthreads();
    }
  }
  if (tid < 512)
    si[tid] = (tid < KSEL) ? (unsigned int)(LL - 1) -
                                 (unsigned int)(keys[LL - KSEL + tid] & 0xFFFFFFFFu)
                           : 0xFFFFFFFFu;
  __syncthreads();
  for (unsigned int k = 2; k <= 512; k <<= 1) {
    for (unsigned int j = k >> 1; j > 0; j >>= 1) {
      if (tid < 512) {
        const unsigned int i = tid;
        const unsigned int ixj = i ^ j;
        if (ixj > i) {
          const bool up = ((i & k) == 0);
          const unsigned int a = si[i], c = si[ixj];
          if ((a > c) == up) { si[i] = c; si[ixj] = a; }
        }
      }
      __syncthreads();
    }
  }
  if (tid < KSEL) sel[b * KSEL + tid] = (int)si[tid];
}

// ---------- qkv: 3-term split MFMA; writes split-bf16 Q,K row-major + V transposed
__global__ __launch_bounds__(256) void k_qkv(
    const float* __restrict__ x, const u16* __restrict__ wh, const u16* __restrict__ wl,
    const int* __restrict__ sel,
    u16* __restrict__ qh, u16* __restrict__ ql,
    u16* __restrict__ kh, u16* __restrict__ kl,
    u16* __restrict__ vTh, u16* __restrict__ vTl) {
  __shared__ u16 Ah[128 * PK], Al[128 * PK], Bh[128 * PK], Bl[128 * PK];
  const int t = threadIdx.x;
  const int nt = blockIdx.x, r0 = blockIdx.y * 128;
  const int wid = t >> 6, lane = t & 63;
  const int wy = wid >> 1, wx = wid & 1;
  const int qi = lane & 15, g = lane >> 4;
  f32x4 acc[4][4];
#pragma unroll
  for (int i = 0; i < 4; i++)
#pragma unroll
    for (int j = 0; j < 4; j++) acc[i][j] = (f32x4){0.f, 0.f, 0.f, 0.f};

  const int ar = t >> 1, akk = (t & 1) * 16;
  int rg = r0 + ar;
  rg = rg < MTOT ? rg : MTOT - 1;
  const int bb = rg / KSEL;
  const int tok = sel[rg];
  const float* xr = x + ((long)bb * LL + tok) * DD + akk;
  const int bn = t >> 1, bko = (t & 1) * 16;
  const int arow = wy * 64 + qi;
  const int koff = g * 8;

  for (int s = 0; s < 32; s++) {
    float v[16];
#pragma unroll
    for (int q = 0; q < 4; q++) {
      float4 f = *(const float4*)(xr + s * 32 + q * 4);
      v[q * 4] = f.x; v[q * 4 + 1] = f.y; v[q * 4 + 2] = f.z; v[q * 4 + 3] = f.w;
    }
    ux4 H0, L0, H1, L1;
    cvt8(v, H0, L0);
    cvt8(v + 8, H1, L1);
    *(ux4*)(Ah + ar * PK + akk) = H0;
    *(ux4*)(Ah + ar * PK + akk + 8) = H1;
    *(ux4*)(Al + ar * PK + akk) = L0;
    *(ux4*)(Al + ar * PK + akk + 8) = L1;
    const long wb = ((long)s * NT3 + nt * 128 + bn) * 32 + bko;
    *(ux4*)(Bh + bn * PK + bko) = *(const ux4*)(wh + wb);
    *(ux4*)(Bh + bn * PK + bko + 8) = *(const ux4*)(wh + wb + 8);
    *(ux4*)(Bl + bn * PK + bko) = *(const ux4*)(wl + wb);
    *(ux4*)(Bl + bn * PK + bko + 8) = *(const ux4*)(wl + wb + 8);
    __syncthreads();
    short8 a_h[4], a_l[4];
#pragma unroll
    for (int mi = 0; mi < 4; mi++) {
      a_h[mi] = *(const short8*)(Ah + (arow + mi * 16) * PK + koff);
      a_l[mi] = *(const short8*)(Al + (arow + mi * 16) * PK + koff);
    }
#pragma unroll
    for (int ni = 0; ni < 4; ni++) {
      const int brow = (wx * 64 + ni * 16 + qi) * PK + koff;
      short8 b_h = *(const short8*)(Bh + brow);
      short8 b_l = *(const short8*)(Bl + brow);
#pragma unroll
      for (int mi = 0; mi < 4; mi++) {
        acc[mi][ni] = __builtin_amdgcn_mfma_f32_16x16x32_bf16(a_h[mi], b_h, acc[mi][ni], 0, 0, 0);
        acc[mi][ni] = __builtin_amdgcn_mfma_f32_16x16x32_bf16(a_h[mi], b_l, acc[mi][ni], 0, 0, 0);
        acc[mi][ni] = __builtin_amdgcn_mfma_f32_16x16x32_bf16(a_l[mi], b_h, acc[mi][ni], 0, 0, 0);
      }
    }
    __syncthreads();
  }
  // epilogue: split-bf16 outputs; q/k row-major, v transposed [bh][d][key]
#pragma unroll
  for (int mi = 0; mi < 4; mi++) {
#pragma unroll
    for (int rr = 0; rr < 4; rr++) {
      const int r = r0 + wy * 64 + mi * 16 + g * 4 + rr;
      if (r < MTOT) {
        if (nt < 16) {
          u16* dh = (nt < 8) ? qh : kh;
          u16* dl = (nt < 8) ? ql : kl;
          const long base = (long)r * DD + (nt & 7) * 128 + wx * 64 + qi;
#pragma unroll
          for (int ni = 0; ni < 4; ni++) {
            const float f = acc[mi][ni][rr];
            const u16 hh_ = bfh(f);
            dh[base + ni * 16] = hh_;
            dl[base + ni * 16] = bfh(f - bff(hh_));
          }
        } else {
          const int b2 = r / KSEL;
          const int key = r - b2 * KSEL;
          const int hh = (nt - 16) * 2 + wx;
          const long vbase = ((long)(b2 * 16 + hh) * 64) * VP + key;
#pragma unroll
          for (int ni = 0; ni < 4; ni++) {
            const int d = ni * 16 + qi;
            const float f = acc[mi][ni][rr];
            const u16 hh_ = bfh(f);
            vTh[vbase + (long)d * VP] = hh_;
            vTl[vbase + (long)d * VP] = bfh(f - bff(hh_));
          }
        }
      }
    }
  }
}

// ---------- MFMA flash attention: S^T = K·Q^T (swapped), lane-local softmax ------
__global__ __launch_bounds__(256) void k_attn(
    const u16* __restrict__ qh, const u16* __restrict__ ql,
    const u16* __restrict__ kh, const u16* __restrict__ kl,
    const u16* __restrict__ vh, const u16* __restrict__ vl,
    float* __restrict__ ao) {
  __shared__ u16 Qh[64][72], Ql[64][72], Kh[64][72], Kl[64][72],
                 Vh[64][72], Vl[64][72], Ph[64][72];
  const int t = threadIdx.x;
  const int qt = blockIdx.x, h = blockIdx.y, b = blockIdx.z;
  const int w = t >> 6, lane = t & 63;
  const int g = lane >> 4, qi = lane & 15;
  const int sr = t >> 2, sc = (t & 3) * 16;
  const ux4 zz = (ux4){0u, 0u, 0u, 0u};
  // stage Q tile (rows = local q)
  {
    const int q_ = qt * 64 + sr;
    if (q_ < KSEL) {
      const long ga = (long)(b * KSEL + q_) * DD + h * 64 + sc;
      *(ux4*)(&Qh[sr][sc]) = *(const ux4*)(qh + ga);
      *(ux4*)(&Qh[sr][sc + 8]) = *(const ux4*)(qh + ga + 8);
      *(ux4*)(&Ql[sr][sc]) = *(const ux4*)(ql + ga);
      *(ux4*)(&Ql[sr][sc + 8]) = *(const ux4*)(ql + ga + 8);
    } else {
      *(ux4*)(&Qh[sr][sc]) = zz; *(ux4*)(&Qh[sr][sc + 8]) = zz;
      *(ux4*)(&Ql[sr][sc]) = zz; *(ux4*)(&Ql[sr][sc + 8]) = zz;
    }
  }
  __syncthreads();
  // preload this wave's Q fragments (B-operand), then Q LDS is read-only done
  short8 qf_h[2], qf_l[2];
#pragma unroll
  for (int ks = 0; ks < 2; ks++) {
    qf_h[ks] = *(const short8*)(&Qh[w * 16 + qi][ks * 32 + g * 8]);
    qf_l[ks] = *(const short8*)(&Ql[w * 16 + qi][ks * 32 + g * 8]);
  }
  float m = -1e30f, l = 0.f;
  f32x4 o[4];
#pragma unroll
  for (int dt = 0; dt < 4; dt++) o[dt] = (f32x4){0.f, 0.f, 0.f, 0.f};

  for (int kt = 0; kt < 7; kt++) {
    __syncthreads();
    {  // stage K tile (rows = key)
      const int gk = kt * 64 + sr;
      if (gk < KSEL) {
        const long ga = (long)(b * KSEL + gk) * DD + h * 64 + sc;
        *(ux4*)(&Kh[sr][sc]) = *(const ux4*)(kh + ga);
        *(ux4*)(&Kh[sr][sc + 8]) = *(const ux4*)(kh + ga + 8);
        *(ux4*)(&Kl[sr][sc]) = *(const ux4*)(kl + ga);
        *(ux4*)(&Kl[sr][sc + 8]) = *(const ux4*)(kl + ga + 8);
      } else {
        *(ux4*)(&Kh[sr][sc]) = zz; *(ux4*)(&Kh[sr][sc + 8]) = zz;
        *(ux4*)(&Kl[sr][sc]) = zz; *(ux4*)(&Kl[sr][sc + 8]) = zz;
      }
    }
    {  // stage V^T tile (rows = d, cols = key)
      const long va = ((long)((b * 16 + h) * 64 + sr)) * VP + kt * 64 + sc;
      const int key0 = kt * 64 + sc;
      if (key0 + 15 < KSEL) {
        *(ux4*)(&Vh[sr][sc]) = *(const ux4*)(vh + va);
        *(ux4*)(&Vh[sr][sc + 8]) = *(const ux4*)(vh + va + 8);
        *(ux4*)(&Vl[sr][sc]) = *(const ux4*)(vl + va);
        *(ux4*)(&Vl[sr][sc + 8]) = *(const ux4*)(vl + va + 8);
      } else {
#pragma unroll
        for (int j = 0; j < 16; j++) {
          const bool ok = (key0 + j) < KSEL;
          Vh[sr][sc + j] = ok ? vh[va + j] : (u16)0;
          Vl[sr][sc + j] = ok ? vl[va + j] : (u16)0;
        }
      }
    }
    __syncthreads();
    // S^T[key][q]: A = K, B = Q (3-term split)
    f32x4 s[4];
#pragma unroll
    for (int mt = 0; mt < 4; mt++) s[mt] = (f32x4){0.f, 0.f, 0.f, 0.f};
#pragma unroll
    for (int ks = 0; ks < 2; ks++) {
#pragma unroll
      for (int mt = 0; mt < 4; mt++) {
        short8 a_h = *(const short8*)(&Kh[mt * 16 + qi][ks * 32 + g * 8]);
        short8 a_l = *(const short8*)(&Kl[mt * 16 + qi][ks * 32 + g * 8]);
        s[mt] = __builtin_amdgcn_mfma_f32_16x16x32_bf16(a_h, qf_h[ks], s[mt], 0, 0, 0);
        s[mt] = __builtin_amdgcn_mfma_f32_16x16x32_bf16(a_h, qf_l[ks], s[mt], 0, 0, 0);
        s[mt] = __builtin_amdgcn_mfma_f32_16x16x32_bf16(a_l, qf_h[ks], s[mt], 0, 0, 0);
      }
    }
    // online softmax; all state lane-local in q = qi
    float tmax = -1e30f;
#pragma unroll
    for (int mt = 0; mt < 4; mt++)
#pragma unroll
      for (int r = 0; r < 4; r++) {
        const int key = kt * 64 + mt * 16 + g * 4 + r;
        const float sv = s[mt][r] * 0.125f;
        s[mt][r] = sv;
        if (key < KSEL) tmax = fmaxf(tmax, sv);
      }
    tmax = fmaxf(tmax, __shfl_xor(tmax, 16));
    tmax = fmaxf(tmax, __shfl_xor(tmax, 32));
    const float mn = fmaxf(m, tmax);
    const float scale = __expf(m - mn);
    float part = 0.f;
#pragma unroll
    for (int mt = 0; mt < 4; mt++)
#pragma unroll
      for (int r = 0; r < 4; r++) {
        const int key = kt * 64 + mt * 16 + g * 4 + r;
        const float p = (key < KSEL) ? __expf(s[mt][r] - mn) : 0.f;
        part += p;
        Ph[w * 16 + qi][mt * 16 + g * 4 + r] = bfh(p);
      }
    part += __shfl_xor(part, 16);
    part += __shfl_xor(part, 32);
    l = l * scale + part;
    m = mn;
#pragma unroll
    for (int dt = 0; dt < 4; dt++)
#pragma unroll
      for (int r = 0; r < 4; r++) o[dt][r] *= scale;
    // O^T[d][q] += V^T · P : A = V^T (2-term), B = P (hi)
#pragma unroll
    for (int ks = 0; ks < 2; ks++) {
      const short8 b_p = *(const short8*)(&Ph[w * 16 + qi][ks * 32 + g * 8]);
#pragma unroll
      for (int dt = 0; dt < 4; dt++) {
        short8 a_h = *(const short8*)(&Vh[dt * 16 + qi][ks * 32 + g * 8]);
        short8 a_l = *(const short8*)(&Vl[dt * 16 + qi][ks * 32 + g * 8]);
        o[dt] = __builtin_amdgcn_mfma_f32_16x16x32_bf16(a_h, b_p, o[dt], 0, 0, 0);
        o[dt] = __builtin_amdgcn_mfma_f32_16x16x32_bf16(a_l, b_p, o[dt], 0, 0, 0);
      }
    }
  }
  // epilogue: O / l, write ao fp32 (lane owns q = w*16+qi; regs are consecutive d)
  const int q_ = qt * 64 + w * 16 + qi;
  if (q_ < KSEL) {
    const float inv = 1.f / l;
    const long base_o = ((long)(b * KSEL + q_)) * DD + h * 64;
#pragma unroll
    for (int dt = 0; dt < 4; dt++) {
      float4 vv = make_float4(o[dt][0] * inv, o[dt][1] * inv, o[dt][2] * inv, o[dt][3] * inv);
      *(float4*)(ao + base_o + dt * 16 + g * 4) = vv;
    }
  }
}

// ---------- out-proj + scatter + residual : 3-term split MFMA ----------
__global__ __launch_bounds__(256) void k_oproj(
    const float* __restrict__ ao, const u16* __restrict__ wh, const u16* __restrict__ wl,
    const int* __restrict__ sel, const float* __restrict__ x,
    const float* __restrict__ resw, float* __restrict__ y) {
  __shared__ u16 Ah[128 * PK], Al[128 * PK], Bh[128 * PK], Bl[128 * PK];
  const int t = threadIdx.x;
  const int nt = blockIdx.x, r0 = blockIdx.y * 128;
  const int wid = t >> 6, lane = t & 63;
  const int wy = wid >> 1, wx = wid & 1;
  f32x4 acc[4][4];
#pragma unroll
  for (int i = 0; i < 4; i++)
#pragma unroll
    for (int j = 0; j < 4; j++) acc[i][j] = (f32x4){0.f, 0.f, 0.f, 0.f};

  const int ar = t >> 1, akk = (t & 1) * 16;
  int rg = r0 + ar;
  rg = rg < MTOT ? rg : MTOT - 1;
  const float* arp = ao + (long)rg * DD + akk;
  const int bn = t >> 1, bko = (t & 1) * 16;
  const int arow = wy * 64 + (lane & 15);
  const int koff = (lane >> 4) * 8;

  for (int s = 0; s < 32; s++) {
    float v[16];
#pragma unroll
    for (int q = 0; q < 4; q++) {
      float4 f = *(const float4*)(arp + s * 32 + q * 4);
      v[q * 4] = f.x; v[q * 4 + 1] = f.y; v[q * 4 + 2] = f.z; v[q * 4 + 3] = f.w;
    }
    ux4 H0, L0, H1, L1;
    cvt8(v, H0, L0);
    cvt8(v + 8, H1, L1);
    *(ux4*)(Ah + ar * PK + akk) = H0;
    *(ux4*)(Ah + ar * PK + akk + 8) = H1;
    *(ux4*)(Al + ar * PK + akk) = L0;
    *(ux4*)(Al + ar * PK + akk + 8) = L1;
    const long wb = ((long)s * DD + nt * 128 + bn) * 32 + bko;
    *(ux4*)(Bh + bn * PK + bko) = *(const ux4*)(wh + wb);
    *(ux4*)(Bh + bn * PK + bko + 8) = *(const ux4*)(wh + wb + 8);
    *(ux4*)(Bl + bn * PK + bko) = *(const ux4*)(wl + wb);
    *(ux4*)(Bl + bn * PK + bko + 8) = *(const ux4*)(wl + wb + 8);
    __syncthreads();
    short8 a_h[4], a_l[4];
#pragma unroll
    for (int mi = 0; mi < 4; mi++) {
      a_h[mi] = *(const short8*)(Ah + (arow + mi * 16) * PK + koff);
      a_l[mi] = *(const short8*)(Al + (arow + mi * 16) * PK + koff);
    }
#pragma unroll
    for (int ni = 0; ni < 4; ni++) {
      const int brow = (wx * 64 + ni * 16 + (lane & 15)) * PK + koff;
      short8 b_h = *(const short8*)(Bh + brow);
      short8 b_l = *(const short8*)(Bl + brow);
#pragma unroll
      for (int mi = 0; mi < 4; mi++) {
        acc[mi][ni] = __builtin_amdgcn_mfma_f32_16x16x32_bf16(a_h[mi], b_h, acc[mi][ni], 0, 0, 0);
        acc[mi][ni] = __builtin_amdgcn_mfma_f32_16x16x32_bf16(a_h[mi], b_l, acc[mi][ni], 0, 0, 0);
        acc[mi][ni] = __builtin_amdgcn_mfma_f32_16x16x32_bf16(a_l[mi], b_h, acc[mi][ni], 0, 0, 0);
      }
    }
    __syncthreads();
  }
  const float rw = resw[0];
#pragma unroll
  for (int mi = 0; mi < 4; mi++)
#pragma unroll
    for (int rr = 0; rr < 4; rr++) {
      const int r = r0 + wy * 64 + mi * 16 + (lane >> 4) * 4 + rr;
      if (r < MTOT) {
        const int bb = r / KSEL;
        const int tok = sel[r];
        const long off = ((long)bb * LL + tok) * DD + nt * 128 + wx * 64 + (lane & 15);
#pragma unroll
        for (int ni = 0; ni < 4; ni++)
          y[off + ni * 16] = fmaf(rw, acc[mi][ni][rr], x[off + ni * 16]);
      }
    }
}

extern "C" void kernel_launch(void* const* d_in, const int* in_sizes, int n_in,
                              void* d_out, int out_size, void* d_ws, size_t ws_size,
                              hipStream_t stream) {
  const float* x = (const float*)d_in[0];
  const float* w1 = (const float*)d_in[1];
  const float* b1 = (const float*)d_in[2];
  const float* w2 = (const float*)d_in[3];
  // d_in[4] = b2: constant shift through monotone sigmoid -> irrelevant to top-k
  const float* wqkv = (const float*)d_in[5];
  const float* wout = (const float*)d_in[6];
  const float* resw = (const float*)d_in[7];
  float* y = (float*)d_out;

  char* ws = (char*)d_ws;
  float* z = (float*)(ws);                  // 131072 B
  int* sel = (int*)(ws + 131072);           // 16384 B
  u16* w1h = (u16*)(ws + 147456);           // 524288 B
  u16* w1l = (u16*)(ws + 671744);           // 524288 B
  u16* wqh = (u16*)(ws + 1196032);          // 6291456 B
  u16* wql = (u16*)(ws + 7487488);          // 6291456 B
  u16* woh = (u16*)(ws + 13778944);         // 2097152 B
  u16* wol = (u16*)(ws + 15876096);         // 2097152 B
  u16* qh = (u16*)(ws + 17973248);          // 6701056 B (3272*1024 u16)
  u16* ql = (u16*)(ws + 24674304);          // 6701056 B
  u16* kh = (u16*)(ws + 31375360);          // 6701056 B
  u16* kl = (u16*)(ws + 38076416);          // 6701056 B
  u16* vTh = (u16*)(ws + 44777472);         // 7340032 B (128*64*448 u16)
  u16* vTl = (u16*)(ws + 52117504);         // 7340032 B
  float* ao = (float*)(ws + 59457536);      // 13402112 B -> 72.9 MB total

  k_prep<<<dim3(1, 32), 256, 0, stream>>>(w1, 256, w1h, w1l);
  k_prep<<<dim3(12, 32), 256, 0, stream>>>(wqkv, NT3, wqh, wql);
  k_prep<<<dim3(4, 32), 256, 0, stream>>>(wout, DD, woh, wol);
  k_score<<<512, 256, 0, stream>>>(x, w1h, w1l, b1, w2, z, y);
  k_topk<<<BB, 1024, 0, stream>>>(z, sel);
  k_qkv<<<dim3(24, 26), 256, 0, stream>>>(x, wqh, wql, sel, qh, ql, kh, kl, vTh, vTl);
  k_attn<<<dim3(7, HH, BB), 256, 0, stream>>>(qh, ql, kh, kl, vTh, vTl, ao);
  k_oproj<<<dim3(8, 26), 256, 0, stream>>>(ao, woh, wol, sel, x, resw, y);
}

// Round 4
// 386.447 us; speedup vs baseline: 3.0199x; 1.0518x over previous
//
#include <hip/hip_runtime.h>
#include <cstdint>

#define BB 8
#define LL 4096
#define DD 1024
#define HH 16
#define KSEL 409
#define NT3 3072
#define MTOT (BB * KSEL)   // 3272 flat selected rows
#define PK 40              // LDS pitch in bf16 for 32-wide k tiles (+8 pad)
#define VP 448             // vT key-pitch

typedef unsigned short u16;
typedef __attribute__((ext_vector_type(4))) unsigned int ux4;
typedef __attribute__((ext_vector_type(4))) unsigned short us4;
typedef __attribute__((ext_vector_type(8))) short short8;
typedef __attribute__((ext_vector_type(4))) float f32x4;

__device__ __forceinline__ u16 bfh(float f) {
  unsigned u = __float_as_uint(f);
  return (u16)((u + 0x7fffu + ((u >> 16) & 1u)) >> 16);
}
__device__ __forceinline__ float bff(u16 h) { return __uint_as_float(((unsigned)h) << 16); }

__device__ __forceinline__ void cvt8(const float* v, ux4& H, ux4& L) {
#pragma unroll
  for (int i = 0; i < 4; i++) {
    u16 h0 = bfh(v[2 * i]), h1 = bfh(v[2 * i + 1]);
    u16 l0 = bfh(v[2 * i] - bff(h0));
    u16 l1 = bfh(v[2 * i + 1] - bff(h1));
    H[i] = (unsigned)h0 | ((unsigned)h1 << 16);
    L[i] = (unsigned)l0 | ((unsigned)l1 << 16);
  }
}

// ---------- prep: fp32 weight [K][N] -> split-bf16 K-packed [s][n][32] ----------
__global__ __launch_bounds__(256) void k_prep(const float* __restrict__ w, int N,
                                              u16* __restrict__ h, u16* __restrict__ l) {
  __shared__ float T[32][257];
  const int t = threadIdx.x;
  const int n0 = blockIdx.x * 256, s = blockIdx.y;
#pragma unroll 4
  for (int r = 0; r < 32; r++) T[r][t] = w[((long)(s * 32 + r)) * N + n0 + t];
  __syncthreads();
  const long base = ((long)s * N + n0 + t) * 32;
#pragma unroll
  for (int q = 0; q < 4; q++) {
    float v[8];
#pragma unroll
    for (int i = 0; i < 8; i++) v[i] = T[q * 8 + i][t];
    ux4 H, L;
    cvt8(v, H, L);
    *(ux4*)(h + base + q * 8) = H;
    *(ux4*)(l + base + q * 8) = L;
  }
}

// ---------- scorer: BM=128, 512 thr, 8 waves (2x4); 4-term split MFMA ----------
__global__ __launch_bounds__(512) void k_score(
    const float* __restrict__ x, const u16* __restrict__ w1h, const u16* __restrict__ w1l,
    const float* __restrict__ b1, const float* __restrict__ w2,
    float* __restrict__ z, float* __restrict__ y) {
  __shared__ u16 Ah[128 * PK], Al[128 * PK], Bh[256 * PK], Bl[256 * PK];
  __shared__ float zp[128][4];
  const int t = threadIdx.x;
  const long t0 = (long)blockIdx.x * 128;
  const int wid = t >> 6, lane = t & 63;
  const int wy = wid >> 2, wx = wid & 3;
  const int g = lane >> 4, qi = lane & 15;
  f32x4 acc[4][4];
#pragma unroll
  for (int i = 0; i < 4; i++)
#pragma unroll
    for (int j = 0; j < 4; j++) acc[i][j] = (f32x4){0.f, 0.f, 0.f, 0.f};

  const int ar = t >> 2, ak = (t & 3) * 8;
  const float* xrow = x + (t0 + ar) * DD + ak;
  float* yrow = y + (t0 + ar) * DD + ak;
  const int bn = t >> 1, bko = (t & 1) * 16;

  for (int s = 0; s < 32; s++) {
    float4 va = *(const float4*)(xrow + s * 32);
    float4 vb = *(const float4*)(xrow + s * 32 + 4);
    *(float4*)(yrow + s * 32) = va;          // write-through residual base y = x
    *(float4*)(yrow + s * 32 + 4) = vb;
    float v[8] = {va.x, va.y, va.z, va.w, vb.x, vb.y, vb.z, vb.w};
    ux4 H, L;
    cvt8(v, H, L);
    *(ux4*)(Ah + ar * PK + ak) = H;
    *(ux4*)(Al + ar * PK + ak) = L;
    const long wb = ((long)s * 256 + bn) * 32 + bko;
    *(ux4*)(Bh + bn * PK + bko) = *(const ux4*)(w1h + wb);
    *(ux4*)(Bh + bn * PK + bko + 8) = *(const ux4*)(w1h + wb + 8);
    *(ux4*)(Bl + bn * PK + bko) = *(const ux4*)(w1l + wb);
    *(ux4*)(Bl + bn * PK + bko + 8) = *(const ux4*)(w1l + wb + 8);
    __syncthreads();
    short8 a_h[4], a_l[4];
#pragma unroll
    for (int mi = 0; mi < 4; mi++) {
      const int row = (wy * 64 + mi * 16 + qi) * PK + g * 8;
      a_h[mi] = *(const short8*)(Ah + row);
      a_l[mi] = *(const short8*)(Al + row);
    }
#pragma unroll
    for (int ni = 0; ni < 4; ni++) {
      const int brow = (wx * 64 + ni * 16 + qi) * PK + g * 8;
      short8 b_h = *(const short8*)(Bh + brow);
      short8 b_l = *(const short8*)(Bl + brow);
#pragma unroll
      for (int mi = 0; mi < 4; mi++) {
        acc[mi][ni] = __builtin_amdgcn_mfma_f32_16x16x32_bf16(a_h[mi], b_h, acc[mi][ni], 0, 0, 0);
        acc[mi][ni] = __builtin_amdgcn_mfma_f32_16x16x32_bf16(a_h[mi], b_l, acc[mi][ni], 0, 0, 0);
        acc[mi][ni] = __builtin_amdgcn_mfma_f32_16x16x32_bf16(a_l[mi], b_h, acc[mi][ni], 0, 0, 0);
        acc[mi][ni] = __builtin_amdgcn_mfma_f32_16x16x32_bf16(a_l[mi], b_l, acc[mi][ni], 0, 0, 0);
      }
    }
    __syncthreads();
  }
  // epilogue: relu + layer-2 (fp32), reduce over qi then across col-waves
  float part[4][4];
#pragma unroll
  for (int mi = 0; mi < 4; mi++)
#pragma unroll
    for (int r = 0; r < 4; r++) part[mi][r] = 0.f;
#pragma unroll
  for (int ni = 0; ni < 4; ni++) {
    const int col = wx * 64 + ni * 16 + qi;
    const float b1v = b1[col], w2v = w2[col];
#pragma unroll
    for (int mi = 0; mi < 4; mi++)
#pragma unroll
      for (int r = 0; r < 4; r++) {
        float hv = acc[mi][ni][r] + b1v;
        hv = hv > 0.f ? hv : 0.f;
        part[mi][r] = fmaf(hv, w2v, part[mi][r]);
      }
  }
#pragma unroll
  for (int mi = 0; mi < 4; mi++)
#pragma unroll
    for (int r = 0; r < 4; r++) {
      float p = part[mi][r];
      p += __shfl_xor(p, 1, 16);
      p += __shfl_xor(p, 2, 16);
      p += __shfl_xor(p, 4, 16);
      p += __shfl_xor(p, 8, 16);
      part[mi][r] = p;
    }
  if (qi == 0) {
#pragma unroll
    for (int mi = 0; mi < 4; mi++)
#pragma unroll
      for (int r = 0; r < 4; r++)
        zp[wy * 64 + mi * 16 + g * 4 + r][wx] = part[mi][r];
  }
  __syncthreads();
  if (t < 128) z[t0 + t] = (zp[t][0] + zp[t][1]) + (zp[t][2] + zp[t][3]);
}

// ---------- per-batch top-k via bitonic sort ----------
__global__ __launch_bounds__(1024) void k_topk(const float* __restrict__ z,
                                               int* __restrict__ sel) {
  __shared__ unsigned long long keys[LL];
  __shared__ unsigned int si[512];
  const int b = blockIdx.x;
  const int tid = threadIdx.x;
#pragma unroll
  for (int s = 0; s < 4; s++) {
    const int i = tid + s * 1024;
    unsigned int u = __float_as_uint(z[b * LL + i]);
    u = (u & 0x80000000u) ? ~u : (u | 0x80000000u);
    keys[i] = ((unsigned long long)u << 32) | (unsigned int)(LL - 1 - i);
  }
  __syncthreads();
  for (unsigned int k = 2; k <= LL; k <<= 1) {
    for (unsigned int j = k >> 1; j > 0; j >>= 1) {
#pragma unroll
      for (int s = 0; s < 4; s++) {
        const unsigned int i = tid + s * 1024;
        const unsigned int ixj = i ^ j;
        if (ixj > i) {
          const bool up = ((i & k) == 0);
          const unsigned long long a = keys[i], c = keys[ixj];
          if ((a > c) == up) { keys[i] = c; keys[ixj] = a; }
        }
      }
      __syncthreads();
    }
  }
  if (tid < 512)
    si[tid] = (tid < KSEL) ? (unsigned int)(LL - 1) -
                                 (unsigned int)(keys[LL - KSEL + tid] & 0xFFFFFFFFu)
                           : 0xFFFFFFFFu;
  __syncthreads();
  for (unsigned int k = 2; k <= 512; k <<= 1) {
    for (unsigned int j = k >> 1; j > 0; j >>= 1) {
      if (tid < 512) {
        const unsigned int i = tid;
        const unsigned int ixj = i ^ j;
        if (ixj > i) {
          const bool up = ((i & k) == 0);
          const unsigned int a = si[i], c = si[ixj];
          if ((a > c) == up) { si[i] = c; si[ixj] = a; }
        }
      }
      __syncthreads();
    }
  }
  if (tid < KSEL) sel[b * KSEL + tid] = (int)si[tid];
}

// ---------- gather + split-convert selected rows once ----------
__global__ __launch_bounds__(256) void k_xsel(const float* __restrict__ x,
                                              const int* __restrict__ sel,
                                              u16* __restrict__ xsh, u16* __restrict__ xsl) {
  const int t = threadIdx.x;
  const int r = blockIdx.x * 8 + (t >> 5);   // 409 blocks * 8 = 3272 exactly
  const int c = (t & 31) * 32;
  const int b = r / KSEL;
  const int tok = sel[r];
  const float* src = x + ((long)b * LL + tok) * DD + c;
  u16* dh = xsh + (long)r * DD + c;
  u16* dl = xsl + (long)r * DD + c;
#pragma unroll
  for (int q = 0; q < 4; q++) {
    float4 f0 = *(const float4*)(src + q * 8);
    float4 f1 = *(const float4*)(src + q * 8 + 4);
    float v[8] = {f0.x, f0.y, f0.z, f0.w, f1.x, f1.y, f1.z, f1.w};
    ux4 H, L;
    cvt8(v, H, L);
    *(ux4*)(dh + q * 8) = H;
    *(ux4*)(dl + q * 8) = L;
  }
}

// ---------- qkv: bf16 A from xs; writes split-bf16 Q,K row-major + V^T ----------
__global__ __launch_bounds__(256) void k_qkv(
    const u16* __restrict__ xsh, const u16* __restrict__ xsl,
    const u16* __restrict__ wh, const u16* __restrict__ wl,
    u16* __restrict__ qh, u16* __restrict__ ql,
    u16* __restrict__ kh, u16* __restrict__ kl,
    u16* __restrict__ vTh, u16* __restrict__ vTl) {
  __shared__ u16 Ah[128 * PK], Al[128 * PK], Bh[128 * PK], Bl[128 * PK];
  const int t = threadIdx.x;
  const int nt = blockIdx.x, r0 = blockIdx.y * 128;
  const int wid = t >> 6, lane = t & 63;
  const int wy = wid >> 1, wx = wid & 1;
  const int qi = lane & 15, g = lane >> 4;
  f32x4 acc[4][4];
#pragma unroll
  for (int i = 0; i < 4; i++)
#pragma unroll
    for (int j = 0; j < 4; j++) acc[i][j] = (f32x4){0.f, 0.f, 0.f, 0.f};

  const int ar = t >> 1, akk = (t & 1) * 16;
  int rg = r0 + ar;
  rg = rg < MTOT ? rg : MTOT - 1;
  const u16* xh = xsh + (long)rg * DD + akk;
  const u16* xl = xsl + (long)rg * DD + akk;
  const int bn = t >> 1, bko = (t & 1) * 16;
  const int arow = wy * 64 + qi;
  const int koff = g * 8;

  for (int s = 0; s < 32; s++) {
    *(ux4*)(Ah + ar * PK + akk) = *(const ux4*)(xh + s * 32);
    *(ux4*)(Ah + ar * PK + akk + 8) = *(const ux4*)(xh + s * 32 + 8);
    *(ux4*)(Al + ar * PK + akk) = *(const ux4*)(xl + s * 32);
    *(ux4*)(Al + ar * PK + akk + 8) = *(const ux4*)(xl + s * 32 + 8);
    const long wb = ((long)s * NT3 + nt * 128 + bn) * 32 + bko;
    *(ux4*)(Bh + bn * PK + bko) = *(const ux4*)(wh + wb);
    *(ux4*)(Bh + bn * PK + bko + 8) = *(const ux4*)(wh + wb + 8);
    *(ux4*)(Bl + bn * PK + bko) = *(const ux4*)(wl + wb);
    *(ux4*)(Bl + bn * PK + bko + 8) = *(const ux4*)(wl + wb + 8);
    __syncthreads();
    short8 a_h[4], a_l[4];
#pragma unroll
    for (int mi = 0; mi < 4; mi++) {
      a_h[mi] = *(const short8*)(Ah + (arow + mi * 16) * PK + koff);
      a_l[mi] = *(const short8*)(Al + (arow + mi * 16) * PK + koff);
    }
#pragma unroll
    for (int ni = 0; ni < 4; ni++) {
      const int brow = (wx * 64 + ni * 16 + qi) * PK + koff;
      short8 b_h = *(const short8*)(Bh + brow);
      short8 b_l = *(const short8*)(Bl + brow);
#pragma unroll
      for (int mi = 0; mi < 4; mi++) {
        acc[mi][ni] = __builtin_amdgcn_mfma_f32_16x16x32_bf16(a_h[mi], b_h, acc[mi][ni], 0, 0, 0);
        acc[mi][ni] = __builtin_amdgcn_mfma_f32_16x16x32_bf16(a_h[mi], b_l, acc[mi][ni], 0, 0, 0);
        acc[mi][ni] = __builtin_amdgcn_mfma_f32_16x16x32_bf16(a_l[mi], b_h, acc[mi][ni], 0, 0, 0);
      }
    }
    __syncthreads();
  }
  // epilogue: split-bf16 outputs; q/k row-major, v transposed [bh][d][key]
#pragma unroll
  for (int mi = 0; mi < 4; mi++) {
#pragma unroll
    for (int rr = 0; rr < 4; rr++) {
      const int r = r0 + wy * 64 + mi * 16 + g * 4 + rr;
      if (r < MTOT) {
        if (nt < 16) {
          u16* dh = (nt < 8) ? qh : kh;
          u16* dl = (nt < 8) ? ql : kl;
          const long base = (long)r * DD + (nt & 7) * 128 + wx * 64 + qi;
#pragma unroll
          for (int ni = 0; ni < 4; ni++) {
            const float f = acc[mi][ni][rr];
            const u16 hh_ = bfh(f);
            dh[base + ni * 16] = hh_;
            dl[base + ni * 16] = bfh(f - bff(hh_));
          }
        } else {
          const int b2 = r / KSEL;
          const int key = r - b2 * KSEL;
          const int hh = (nt - 16) * 2 + wx;
          const long vbase = ((long)(b2 * 16 + hh) * 64) * VP + key;
#pragma unroll
          for (int ni = 0; ni < 4; ni++) {
            const int d = ni * 16 + qi;
            const float f = acc[mi][ni][rr];
            const u16 hh_ = bfh(f);
            vTh[vbase + (long)d * VP] = hh_;
            vTl[vbase + (long)d * VP] = bfh(f - bff(hh_));
          }
        }
      }
    }
  }
}

// ---------- MFMA flash attention (swapped QK^T, lane-local softmax) ----------
__global__ __launch_bounds__(256) void k_attn(
    const u16* __restrict__ qh, const u16* __restrict__ ql,
    const u16* __restrict__ kh, const u16* __restrict__ kl,
    const u16* __restrict__ vh, const u16* __restrict__ vl,
    u16* __restrict__ aoh, u16* __restrict__ aol) {
  __shared__ u16 Qh[64][72], Ql[64][72], Kh[64][72], Kl[64][72],
                 Vh[64][72], Vl[64][72], Ph[64][72];
  const int t = threadIdx.x;
  const int qt = blockIdx.x, h = blockIdx.y, b = blockIdx.z;
  const int w = t >> 6, lane = t & 63;
  const int g = lane >> 4, qi = lane & 15;
  const int sr = t >> 2, sc = (t & 3) * 16;
  const ux4 zz = (ux4){0u, 0u, 0u, 0u};
  {
    const int q_ = qt * 64 + sr;
    if (q_ < KSEL) {
      const long ga = (long)(b * KSEL + q_) * DD + h * 64 + sc;
      *(ux4*)(&Qh[sr][sc]) = *(const ux4*)(qh + ga);
      *(ux4*)(&Qh[sr][sc + 8]) = *(const ux4*)(qh + ga + 8);
      *(ux4*)(&Ql[sr][sc]) = *(const ux4*)(ql + ga);
      *(ux4*)(&Ql[sr][sc + 8]) = *(const ux4*)(ql + ga + 8);
    } else {
      *(ux4*)(&Qh[sr][sc]) = zz; *(ux4*)(&Qh[sr][sc + 8]) = zz;
      *(ux4*)(&Ql[sr][sc]) = zz; *(ux4*)(&Ql[sr][sc + 8]) = zz;
    }
  }
  __syncthreads();
  short8 qf_h[2], qf_l[2];
#pragma unroll
  for (int ks = 0; ks < 2; ks++) {
    qf_h[ks] = *(const short8*)(&Qh[w * 16 + qi][ks * 32 + g * 8]);
    qf_l[ks] = *(const short8*)(&Ql[w * 16 + qi][ks * 32 + g * 8]);
  }
  float m = -1e30f, l = 0.f;
  f32x4 o[4];
#pragma unroll
  for (int dt = 0; dt < 4; dt++) o[dt] = (f32x4){0.f, 0.f, 0.f, 0.f};

  for (int kt = 0; kt < 7; kt++) {
    __syncthreads();
    {
      const int gk = kt * 64 + sr;
      if (gk < KSEL) {
        const long ga = (long)(b * KSEL + gk) * DD + h * 64 + sc;
        *(ux4*)(&Kh[sr][sc]) = *(const ux4*)(kh + ga);
        *(ux4*)(&Kh[sr][sc + 8]) = *(const ux4*)(kh + ga + 8);
        *(ux4*)(&Kl[sr][sc]) = *(const ux4*)(kl + ga);
        *(ux4*)(&Kl[sr][sc + 8]) = *(const ux4*)(kl + ga + 8);
      } else {
        *(ux4*)(&Kh[sr][sc]) = zz; *(ux4*)(&Kh[sr][sc + 8]) = zz;
        *(ux4*)(&Kl[sr][sc]) = zz; *(ux4*)(&Kl[sr][sc + 8]) = zz;
      }
    }
    {
      const long va = ((long)((b * 16 + h) * 64 + sr)) * VP + kt * 64 + sc;
      const int key0 = kt * 64 + sc;
      if (key0 + 15 < KSEL) {
        *(ux4*)(&Vh[sr][sc]) = *(const ux4*)(vh + va);
        *(ux4*)(&Vh[sr][sc + 8]) = *(const ux4*)(vh + va + 8);
        *(ux4*)(&Vl[sr][sc]) = *(const ux4*)(vl + va);
        *(ux4*)(&Vl[sr][sc + 8]) = *(const ux4*)(vl + va + 8);
      } else {
#pragma unroll
        for (int j = 0; j < 16; j++) {
          const bool ok = (key0 + j) < KSEL;
          Vh[sr][sc + j] = ok ? vh[va + j] : (u16)0;
          Vl[sr][sc + j] = ok ? vl[va + j] : (u16)0;
        }
      }
    }
    __syncthreads();
    f32x4 s[4];
#pragma unroll
    for (int mt = 0; mt < 4; mt++) s[mt] = (f32x4){0.f, 0.f, 0.f, 0.f};
#pragma unroll
    for (int ks = 0; ks < 2; ks++) {
#pragma unroll
      for (int mt = 0; mt < 4; mt++) {
        short8 a_h = *(const short8*)(&Kh[mt * 16 + qi][ks * 32 + g * 8]);
        short8 a_l = *(const short8*)(&Kl[mt * 16 + qi][ks * 32 + g * 8]);
        s[mt] = __builtin_amdgcn_mfma_f32_16x16x32_bf16(a_h, qf_h[ks], s[mt], 0, 0, 0);
        s[mt] = __builtin_amdgcn_mfma_f32_16x16x32_bf16(a_h, qf_l[ks], s[mt], 0, 0, 0);
        s[mt] = __builtin_amdgcn_mfma_f32_16x16x32_bf16(a_l, qf_h[ks], s[mt], 0, 0, 0);
      }
    }
    float tmax = -1e30f;
#pragma unroll
    for (int mt = 0; mt < 4; mt++)
#pragma unroll
      for (int r = 0; r < 4; r++) {
        const int key = kt * 64 + mt * 16 + g * 4 + r;
        const float sv = s[mt][r] * 0.125f;
        s[mt][r] = sv;
        if (key < KSEL) tmax = fmaxf(tmax, sv);
      }
    tmax = fmaxf(tmax, __shfl_xor(tmax, 16));
    tmax = fmaxf(tmax, __shfl_xor(tmax, 32));
    const float mn = fmaxf(m, tmax);
    const float scale = __expf(m - mn);
    float part = 0.f;
#pragma unroll
    for (int mt = 0; mt < 4; mt++)
#pragma unroll
      for (int r = 0; r < 4; r++) {
        const int key = kt * 64 + mt * 16 + g * 4 + r;
        const float p = (key < KSEL) ? __expf(s[mt][r] - mn) : 0.f;
        part += p;
        Ph[w * 16 + qi][mt * 16 + g * 4 + r] = bfh(p);
      }
    part += __shfl_xor(part, 16);
    part += __shfl_xor(part, 32);
    l = l * scale + part;
    m = mn;
#pragma unroll
    for (int dt = 0; dt < 4; dt++)
#pragma unroll
      for (int r = 0; r < 4; r++) o[dt][r] *= scale;
#pragma unroll
    for (int ks = 0; ks < 2; ks++) {
      const short8 b_p = *(const short8*)(&Ph[w * 16 + qi][ks * 32 + g * 8]);
#pragma unroll
      for (int dt = 0; dt < 4; dt++) {
        short8 a_h = *(const short8*)(&Vh[dt * 16 + qi][ks * 32 + g * 8]);
        short8 a_l = *(const short8*)(&Vl[dt * 16 + qi][ks * 32 + g * 8]);
        o[dt] = __builtin_amdgcn_mfma_f32_16x16x32_bf16(a_h, b_p, o[dt], 0, 0, 0);
        o[dt] = __builtin_amdgcn_mfma_f32_16x16x32_bf16(a_l, b_p, o[dt], 0, 0, 0);
      }
    }
  }
  // epilogue: O/l -> split-bf16 ao
  const int q_ = qt * 64 + w * 16 + qi;
  if (q_ < KSEL) {
    const float inv = 1.f / l;
    const long base_o = ((long)(b * KSEL + q_)) * DD + h * 64;
#pragma unroll
    for (int dt = 0; dt < 4; dt++) {
      us4 h4, l4;
#pragma unroll
      for (int rr = 0; rr < 4; rr++) {
        const float f = o[dt][rr] * inv;
        const u16 hh_ = bfh(f);
        h4[rr] = hh_;
        l4[rr] = bfh(f - bff(hh_));
      }
      *(us4*)(aoh + base_o + dt * 16 + g * 4) = h4;
      *(us4*)(aol + base_o + dt * 16 + g * 4) = l4;
    }
  }
}

// ---------- out-proj + scatter + residual : bf16 A, 3-term split MFMA ----------
__global__ __launch_bounds__(256) void k_oproj(
    const u16* __restrict__ aoh, const u16* __restrict__ aol,
    const u16* __restrict__ wh, const u16* __restrict__ wl,
    const int* __restrict__ sel, const float* __restrict__ x,
    const float* __restrict__ resw, float* __restrict__ y) {
  __shared__ u16 Ah[128 * PK], Al[128 * PK], Bh[128 * PK], Bl[128 * PK];
  const int t = threadIdx.x;
  const int nt = blockIdx.x, r0 = blockIdx.y * 128;
  const int wid = t >> 6, lane = t & 63;
  const int wy = wid >> 1, wx = wid & 1;
  f32x4 acc[4][4];
#pragma unroll
  for (int i = 0; i < 4; i++)
#pragma unroll
    for (int j = 0; j < 4; j++) acc[i][j] = (f32x4){0.f, 0.f, 0.f, 0.f};

  const int ar = t >> 1, akk = (t & 1) * 16;
  int rg = r0 + ar;
  rg = rg < MTOT ? rg : MTOT - 1;
  const u16* ah_p = aoh + (long)rg * DD + akk;
  const u16* al_p = aol + (long)rg * DD + akk;
  const int bn = t >> 1, bko = (t & 1) * 16;
  const int arow = wy * 64 + (lane & 15);
  const int koff = (lane >> 4) * 8;

  for (int s = 0; s < 32; s++) {
    *(ux4*)(Ah + ar * PK + akk) = *(const ux4*)(ah_p + s * 32);
    *(ux4*)(Ah + ar * PK + akk + 8) = *(const ux4*)(ah_p + s * 32 + 8);
    *(ux4*)(Al + ar * PK + akk) = *(const ux4*)(al_p + s * 32);
    *(ux4*)(Al + ar * PK + akk + 8) = *(const ux4*)(al_p + s * 32 + 8);
    const long wb = ((long)s * DD + nt * 128 + bn) * 32 + bko;
    *(ux4*)(Bh + bn * PK + bko) = *(const ux4*)(wh + wb);
    *(ux4*)(Bh + bn * PK + bko + 8) = *(const ux4*)(wh + wb + 8);
    *(ux4*)(Bl + bn * PK + bko) = *(const ux4*)(wl + wb);
    *(ux4*)(Bl + bn * PK + bko + 8) = *(const ux4*)(wl + wb + 8);
    __syncthreads();
    short8 a_h[4], a_l[4];
#pragma unroll
    for (int mi = 0; mi < 4; mi++) {
      a_h[mi] = *(const short8*)(Ah + (arow + mi * 16) * PK + koff);
      a_l[mi] = *(const short8*)(Al + (arow + mi * 16) * PK + koff);
    }
#pragma unroll
    for (int ni = 0; ni < 4; ni++) {
      const int brow = (wx * 64 + ni * 16 + (lane & 15)) * PK + koff;
      short8 b_h = *(const short8*)(Bh + brow);
      short8 b_l = *(const short8*)(Bl + brow);
#pragma unroll
      for (int mi = 0; mi < 4; mi++) {
        acc[mi][ni] = __builtin_amdgcn_mfma_f32_16x16x32_bf16(a_h[mi], b_h, acc[mi][ni], 0, 0, 0);
        acc[mi][ni] = __builtin_amdgcn_mfma_f32_16x16x32_bf16(a_h[mi], b_l, acc[mi][ni], 0, 0, 0);
        acc[mi][ni] = __builtin_amdgcn_mfma_f32_16x16x32_bf16(a_l[mi], b_h, acc[mi][ni], 0, 0, 0);
      }
    }
    __syncthreads();
  }
  const float rw = resw[0];
#pragma unroll
  for (int mi = 0; mi < 4; mi++)
#pragma unroll
    for (int rr = 0; rr < 4; rr++) {
      const int r = r0 + wy * 64 + mi * 16 + (lane >> 4) * 4 + rr;
      if (r < MTOT) {
        const int bb = r / KSEL;
        const int tok = sel[r];
        const long off = ((long)bb * LL + tok) * DD + nt * 128 + wx * 64 + (lane & 15);
#pragma unroll
        for (int ni = 0; ni < 4; ni++)
          y[off + ni * 16] = fmaf(rw, acc[mi][ni][rr], x[off + ni * 16]);
      }
    }
}

extern "C" void kernel_launch(void* const* d_in, const int* in_sizes, int n_in,
                              void* d_out, int out_size, void* d_ws, size_t ws_size,
                              hipStream_t stream) {
  const float* x = (const float*)d_in[0];
  const float* w1 = (const float*)d_in[1];
  const float* b1 = (const float*)d_in[2];
  const float* w2 = (const float*)d_in[3];
  // d_in[4] = b2: constant shift through monotone sigmoid -> irrelevant to top-k
  const float* wqkv = (const float*)d_in[5];
  const float* wout = (const float*)d_in[6];
  const float* resw = (const float*)d_in[7];
  float* y = (float*)d_out;

  char* ws = (char*)d_ws;
  float* z = (float*)(ws);                  // 131072 B
  int* sel = (int*)(ws + 131072);           // 16384 B
  u16* w1h = (u16*)(ws + 147456);           // 524288 B
  u16* w1l = (u16*)(ws + 671744);           // 524288 B
  u16* wqh = (u16*)(ws + 1196032);          // 6291456 B
  u16* wql = (u16*)(ws + 7487488);          // 6291456 B
  u16* woh = (u16*)(ws + 13778944);         // 2097152 B
  u16* wol = (u16*)(ws + 15876096);         // 2097152 B
  u16* qh = (u16*)(ws + 17973248);          // 6701056 B
  u16* ql = (u16*)(ws + 24674304);          // 6701056 B
  u16* kh = (u16*)(ws + 31375360);          // 6701056 B
  u16* kl = (u16*)(ws + 38076416);          // 6701056 B
  u16* vTh = (u16*)(ws + 44777472);         // 7340032 B
  u16* vTl = (u16*)(ws + 52117504);         // 7340032 B
  u16* xsh = (u16*)(ws + 59457536);         // 6701056 B (aliased: ao hi after qkv)
  u16* xsl = (u16*)(ws + 66158592);         // 6701056 B (aliased: ao lo after qkv)
  u16* aoh = xsh;  // xs dead after k_qkv; k_attn runs later on same stream
  u16* aol = xsl;

  k_prep<<<dim3(1, 32), 256, 0, stream>>>(w1, 256, w1h, w1l);
  k_prep<<<dim3(12, 32), 256, 0, stream>>>(wqkv, NT3, wqh, wql);
  k_prep<<<dim3(4, 32), 256, 0, stream>>>(wout, DD, woh, wol);
  k_score<<<256, 512, 0, stream>>>(x, w1h, w1l, b1, w2, z, y);
  k_topk<<<BB, 1024, 0, stream>>>(z, sel);
  k_xsel<<<409, 256, 0, stream>>>(x, sel, xsh, xsl);
  k_qkv<<<dim3(24, 26), 256, 0, stream>>>(xsh, xsl, wqh, wql, qh, ql, kh, kl, vTh, vTl);
  k_attn<<<dim3(7, HH, BB), 256, 0, stream>>>(qh, ql, kh, kl, vTh, vTl, aoh, aol);
  k_oproj<<<dim3(8, 26), 256, 0, stream>>>(aoh, aol, woh, wol, sel, x, resw, y);
}